// Round 4
// baseline (1161.694 us; speedup 1.0000x reference)
//
#include <hip/hip_runtime.h>
#include <hip/hip_bf16.h>

// ---------------------------------------------------------------------------
// R4 changes vs R3:
//  * scan_k: R3's full-register weight table (256 VGPRs) spilled to scratch
//    (VGPR_Count=144 proved it). Replaced with a 4-deep rotating register
//    buffer (64 VGPRs) prefetched from padded LDS (stride-20 rows, 2-way max
//    aliasing = free) 4 steps ahead; b/c double-buffered per wave with a
//    register round-trip and NO barriers in the chunk loop.
//  Everything else identical to R3 (passed, 1077 us).
// ---------------------------------------------------------------------------

#define SEQ     2048
#define BATCH   2
#define MROWS   4096      // BATCH*SEQ
#define DMODEL  1024
#define DINNER  2048
#define DFF     4096
#define QKVLD   3072

typedef __attribute__((ext_vector_type(8))) short bf16x8;
typedef __attribute__((ext_vector_type(4))) float f32x4;

__device__ __forceinline__ unsigned short f2b(float x){
    __hip_bfloat16 h = __float2bfloat16(x);
    return *reinterpret_cast<unsigned short*>(&h);
}
__device__ __forceinline__ float b2f(unsigned short u){
    __hip_bfloat16 h;
    *reinterpret_cast<unsigned short*>(&h) = u;
    return __bfloat162float(h);
}
__device__ __forceinline__ float gelu_f(float v){
    float u = 0.7978845608f*(v + 0.044715f*v*v*v);
    float e = __expf(2.f*u);
    float th = 1.f - 2.f*__builtin_amdgcn_rcpf(e + 1.f);
    return 0.5f*v*(1.f + th);
}
__device__ __forceinline__ void gload16(const unsigned short* g, unsigned short* l){
    __builtin_amdgcn_global_load_lds(
        (const __attribute__((address_space(1))) void*)g,
        (__attribute__((address_space(3))) void*)l, 16, 0, 0);
}
template<int CTRL>
__device__ __forceinline__ float dppf(float x){
    int r = __builtin_amdgcn_mov_dpp(__builtin_bit_cast(int, x), CTRL, 0xf, 0xf, false);
    return __builtin_bit_cast(float, r);
}
template<int CTRL>
__device__ __forceinline__ int dppi(int x){
    return __builtin_amdgcn_mov_dpp(x, CTRL, 0xf, 0xf, false);
}

// ---------------- transpose + cast: W (KxN f32) -> Wt (NxK bf16) ----------
__global__ __launch_bounds__(256) void transpose_cast(
    const float* __restrict__ W, unsigned short* __restrict__ Wt, int K, int N)
{
    __shared__ float t[64*65];
    int n0 = blockIdx.x*64, k0 = blockIdx.y*64;
    int c = threadIdx.x & 63, r0 = threadIdx.x >> 6;
    #pragma unroll
    for (int rr = 0; rr < 64; rr += 4)
        t[(rr+r0)*65 + c] = W[(size_t)(k0+rr+r0)*N + n0 + c];
    __syncthreads();
    #pragma unroll
    for (int rr = 0; rr < 64; rr += 4)
        Wt[(size_t)(n0+rr+r0)*K + k0 + c] = f2b(t[c*65 + rr + r0]);
}

// ---------------- concat 3 bias vectors --------------------------------
__global__ __launch_bounds__(256) void concat_bias(
    const float* __restrict__ b0, const float* __restrict__ b1,
    const float* __restrict__ b2, float* __restrict__ o)
{
    int t = blockIdx.x*256 + threadIdx.x;
    float v = (t < 1024) ? b0[t] : (t < 2048 ? b1[t-1024] : b2[t-2048]);
    o[t] = v;
}

// ---------------- layernorm row=1024, f32 in -> bf16 out ------------------
__global__ __launch_bounds__(256) void layernorm_bf16(
    const float* __restrict__ x, const float* __restrict__ g,
    const float* __restrict__ b, unsigned short* __restrict__ out)
{
    int row = blockIdx.x;
    const float4* xr = (const float4*)(x + (size_t)row*DMODEL);
    int tid = threadIdx.x;
    float4 xv = xr[tid];
    float s  = xv.x + xv.y + xv.z + xv.w;
    float ss = xv.x*xv.x + xv.y*xv.y + xv.z*xv.z + xv.w*xv.w;
    #pragma unroll
    for (int d = 32; d > 0; d >>= 1){ s += __shfl_xor(s,d); ss += __shfl_xor(ss,d); }
    __shared__ float sm[8];
    int wv = tid>>6, ln = tid&63;
    if (ln == 0){ sm[wv] = s; sm[4+wv] = ss; }
    __syncthreads();
    s  = sm[0]+sm[1]+sm[2]+sm[3];
    ss = sm[4]+sm[5]+sm[6]+sm[7];
    float mean = s*(1.f/DMODEL);
    float var  = ss*(1.f/DMODEL) - mean*mean;
    float rstd = rsqrtf(var + 1e-5f);
    float4 gv = ((const float4*)g)[tid];
    float4 bv = ((const float4*)b)[tid];
    ushort4 o;
    o.x = f2b((xv.x-mean)*rstd*gv.x + bv.x);
    o.y = f2b((xv.y-mean)*rstd*gv.y + bv.y);
    o.z = f2b((xv.z-mean)*rstd*gv.z + bv.z);
    o.w = f2b((xv.w-mean)*rstd*gv.w + bv.w);
    ((ushort4*)(out + (size_t)row*DMODEL))[tid] = o;
}

// ---------------- GEMM: C[M,N] = act(A[M,K] @ Bt[N,K]^T + bias) (+res) ----
// 128x128 tile, 4 waves, each 64x64. BK=64. global_load_lds staging (m97).
template<int OUT_BF16, int HAS_RES, int ACT>
__global__ __launch_bounds__(256,2) void gemm_bt(
    const unsigned short* __restrict__ A, const unsigned short* __restrict__ Bt,
    const float* __restrict__ bias, const float* __restrict__ res,
    void* __restrict__ outp, int Ndim, int Kdim)
{
    __shared__ unsigned short As[128*64];   // unpadded: required by global_load_lds
    __shared__ unsigned short Bs[128*64];
    int tid = threadIdx.x;
    int lane = tid & 63, wv = tid >> 6;
    int l15 = lane & 15, quad = lane >> 4;
    int m0 = blockIdx.y*128, n0 = blockIdx.x*128;
    int mo = (wv>>1)*64, no = (wv&1)*64;
    int rsub = (lane >> 3);          // 0..7
    int cc8  = (lane & 7)*8;         // element col within 64
    f32x4 zz = {0.f,0.f,0.f,0.f};
    f32x4 acc[4][4];
    #pragma unroll
    for (int i=0;i<4;++i)
      #pragma unroll
      for (int j=0;j<4;++j) acc[i][j] = zz;

    for (int k0 = 0; k0 < Kdim; k0 += 64){
        const unsigned short* Ab = A  + (size_t)(m0 + wv*32 + rsub)*Kdim + k0 + cc8;
        const unsigned short* Bb = Bt + (size_t)(n0 + wv*32 + rsub)*Kdim + k0 + cc8;
        #pragma unroll
        for (int i=0;i<4;++i){
            gload16(Ab + (size_t)(i*8)*Kdim, &As[(wv*32 + i*8)*64]);
            gload16(Bb + (size_t)(i*8)*Kdim, &Bs[(wv*32 + i*8)*64]);
        }
        __syncthreads();
        #pragma unroll
        for (int kc=0;kc<2;++kc){
            bf16x8 af[4], bfr[4];
            #pragma unroll
            for (int t=0;t<4;++t){
                af[t]  = *(const bf16x8*)(&As[(mo + t*16 + l15)*64 + kc*32 + quad*8]);
                bfr[t] = *(const bf16x8*)(&Bs[(no + t*16 + l15)*64 + kc*32 + quad*8]);
            }
            #pragma unroll
            for (int mt=0;mt<4;++mt)
              #pragma unroll
              for (int nt=0;nt<4;++nt)
                acc[mt][nt] = __builtin_amdgcn_mfma_f32_16x16x32_bf16(af[mt], bfr[nt], acc[mt][nt], 0,0,0);
        }
        __syncthreads();
    }
    #pragma unroll
    for (int mt=0;mt<4;++mt){
      #pragma unroll
      for (int nt=0;nt<4;++nt){
        int gn = n0 + no + nt*16 + l15;
        float bval = bias[gn];
        #pragma unroll
        for (int r=0;r<4;++r){
            int gm = m0 + mo + mt*16 + quad*4 + r;
            size_t off = (size_t)gm*Ndim + gn;
            float v = acc[mt][nt][r] + bval;
            if constexpr (HAS_RES) v += res[off];
            if constexpr (ACT == 1) v = gelu_f(v);
            if constexpr (OUT_BF16) ((unsigned short*)outp)[off] = f2b(v);
            else                    ((float*)outp)[off] = v;
        }
      }
    }
}

// ---------------- flash attention, causal, 16 heads of 64 ------------------
// q/k/v live in the fused qkv buffer with row stride QKVLD.
__global__ __launch_bounds__(256,2) void attn_flash(
    const unsigned short* __restrict__ qkv, unsigned short* __restrict__ attn)
{
    __shared__ unsigned short Qs[64*72];
    __shared__ unsigned short Ks[64*72];
    __shared__ unsigned short Vt[64*72];
    __shared__ unsigned short Ps[64*72];
    int bh = blockIdx.y;
    int qt = (int)gridDim.x - 1 - (int)blockIdx.x;
    int q0 = qt*64;
    int tid = threadIdx.x, wv = tid>>6, lane = tid&63;
    int l15 = lane&15, quad = lane>>4;
    const size_t basei = (size_t)(bh>>4)*SEQ*QKVLD + (size_t)(bh&15)*64;
    const unsigned short* q = qkv + basei;
    const unsigned short* k = qkv + basei + DMODEL;
    const unsigned short* v = qkv + basei + 2*DMODEL;
    const size_t baseo = (size_t)(bh>>4)*SEQ*DMODEL + (size_t)(bh&15)*64;

    #pragma unroll
    for (int i=0;i<2;++i){
        int cch = tid + i*256; int r = cch>>3, cc = cch&7;
        *(uint4*)(&Qs[r*72 + cc*8]) = *(const uint4*)(q + (size_t)(q0+r)*QKVLD + cc*8);
    }
    __syncthreads();
    bf16x8 aq0 = *(const bf16x8*)(&Qs[(wv*16 + l15)*72 + quad*8]);
    bf16x8 aq1 = *(const bf16x8*)(&Qs[(wv*16 + l15)*72 + 32 + quad*8]);

    float m_i[4], l_i[4];
    f32x4 zz = {0.f,0.f,0.f,0.f};
    f32x4 o[4];
    #pragma unroll
    for (int r=0;r<4;++r){ m_i[r] = -__builtin_inff(); l_i[r] = 0.f; }
    #pragma unroll
    for (int d=0;d<4;++d) o[d] = zz;

    for (int kt = 0; kt <= qt; ++kt){
        int t0 = kt*64;
        #pragma unroll
        for (int i=0;i<2;++i){
            int cch = tid + i*256; int r = cch>>3, cc = cch&7;
            *(uint4*)(&Ks[r*72 + cc*8]) = *(const uint4*)(k + (size_t)(t0+r)*QKVLD + cc*8);
            uint4 vv = *(const uint4*)(v + (size_t)(t0+r)*QKVLD + cc*8);
            const unsigned short* pv = (const unsigned short*)&vv;
            #pragma unroll
            for (int j=0;j<8;++j) Vt[(cc*8+j)*72 + r] = pv[j];
        }
        __syncthreads();

        f32x4 sc[4];
        #pragma unroll
        for (int st=0;st<4;++st){
            bf16x8 b0 = *(const bf16x8*)(&Ks[(st*16+l15)*72 + quad*8]);
            bf16x8 b1 = *(const bf16x8*)(&Ks[(st*16+l15)*72 + 32 + quad*8]);
            sc[st] = __builtin_amdgcn_mfma_f32_16x16x32_bf16(aq0, b0, zz, 0,0,0);
            sc[st] = __builtin_amdgcn_mfma_f32_16x16x32_bf16(aq1, b1, sc[st], 0,0,0);
        }
        bool diag = (kt == qt);
        float sval[4][4];
        float mrow[4];
        #pragma unroll
        for (int r=0;r<4;++r) mrow[r] = -__builtin_inff();
        #pragma unroll
        for (int st=0;st<4;++st)
          #pragma unroll
          for (int r=0;r<4;++r){
            float svv = sc[st][r]*0.125f;
            if (diag && (st*16 + l15 > wv*16 + quad*4 + r)) svv = -__builtin_inff();
            sval[st][r] = svv;
            mrow[r] = fmaxf(mrow[r], svv);
          }
        #pragma unroll
        for (int d=1; d<16; d<<=1)
          #pragma unroll
          for (int r=0;r<4;++r) mrow[r] = fmaxf(mrow[r], __shfl_xor(mrow[r], d));
        float alpha[4], rsum[4];
        #pragma unroll
        for (int r=0;r<4;++r){
            float mn = fmaxf(m_i[r], mrow[r]);
            alpha[r] = __expf(m_i[r] - mn);
            m_i[r] = mn;
        }
        #pragma unroll
        for (int st=0;st<4;++st)
          #pragma unroll
          for (int r=0;r<4;++r) sval[st][r] = __expf(sval[st][r] - m_i[r]);
        #pragma unroll
        for (int r=0;r<4;++r) rsum[r] = sval[0][r]+sval[1][r]+sval[2][r]+sval[3][r];
        #pragma unroll
        for (int d=1; d<16; d<<=1)
          #pragma unroll
          for (int r=0;r<4;++r) rsum[r] += __shfl_xor(rsum[r], d);
        #pragma unroll
        for (int r=0;r<4;++r) l_i[r] = l_i[r]*alpha[r] + rsum[r];
        #pragma unroll
        for (int st=0;st<4;++st)
          #pragma unroll
          for (int r=0;r<4;++r)
            Ps[(wv*16 + quad*4 + r)*72 + st*16 + l15] = f2b(sval[st][r]);
        #pragma unroll
        for (int d=0;d<4;++d)
          #pragma unroll
          for (int r=0;r<4;++r) o[d][r] = o[d][r]*alpha[r];
        __syncthreads();
        bf16x8 ap0 = *(const bf16x8*)(&Ps[(wv*16 + l15)*72 + quad*8]);
        bf16x8 ap1 = *(const bf16x8*)(&Ps[(wv*16 + l15)*72 + 32 + quad*8]);
        #pragma unroll
        for (int dtile=0;dtile<4;++dtile){
            bf16x8 b0 = *(const bf16x8*)(&Vt[(dtile*16+l15)*72 + quad*8]);
            bf16x8 b1 = *(const bf16x8*)(&Vt[(dtile*16+l15)*72 + 32 + quad*8]);
            o[dtile] = __builtin_amdgcn_mfma_f32_16x16x32_bf16(ap0, b0, o[dtile], 0,0,0);
            o[dtile] = __builtin_amdgcn_mfma_f32_16x16x32_bf16(ap1, b1, o[dtile], 0,0,0);
        }
        __syncthreads();
    }
    #pragma unroll
    for (int r=0;r<4;++r){
        float inv = 1.f/l_i[r];
        int gm = q0 + wv*16 + quad*4 + r;
        #pragma unroll
        for (int dtile=0;dtile<4;++dtile)
            attn[baseo + (size_t)gm*DMODEL + dtile*16 + l15] = f2b(o[dtile][r]*inv);
    }
}

// ---------------- depthwise causal conv(4) + bias + silu -------------------
__global__ __launch_bounds__(256) void conv_silu(
    const unsigned short* __restrict__ xr, const float* __restrict__ cw,
    const float* __restrict__ cb, unsigned short* __restrict__ xm2)
{
    int idx = blockIdx.x*256 + threadIdx.x;
    int r  = idx >> 10;
    int c2 = (idx & 1023)*2;
    int s  = r & (SEQ-1);
    float4 w0 = *(const float4*)(cw + c2*4);
    float4 w1 = *(const float4*)(cw + (c2+1)*4);
    float w0a[4] = {w0.x,w0.y,w0.z,w0.w};
    float w1a[4] = {w1.x,w1.y,w1.z,w1.w};
    float a0 = cb[c2], a1 = cb[c2+1];
    const unsigned short* xrow = xr + (size_t)r*DFF + c2;
    #pragma unroll
    for (int j=0;j<4;++j){
        int sp = s - 3 + j;
        if (sp >= 0){
            int off = (j-3)*DFF;
            unsigned int u = *(const unsigned int*)(xrow + off);
            a0 += w0a[j]*b2f(u & 0xffff);
            a1 += w1a[j]*b2f(u >> 16);
        }
    }
    float s0 = a0 * __builtin_amdgcn_rcpf(1.f + __expf(-a0));
    float s1 = a1 * __builtin_amdgcn_rcpf(1.f + __expf(-a1));
    unsigned int op = (unsigned int)f2b(s0) | ((unsigned int)f2b(s1) << 16);
    *(unsigned int*)(xm2 + (size_t)r*DINNER + c2) = op;
}

// ---------------- xdbl = xm2 @ xp_w + xp_b  (N=32, K=2048) -----------------
__global__ __launch_bounds__(256) void xp_gemm(
    const unsigned short* __restrict__ xm2, const float* __restrict__ w,
    const float* __restrict__ bias, float* __restrict__ xdbl)
{
    int tid = threadIdx.x;
    int lr = tid >> 5, n = tid & 31;
    int row = blockIdx.x*8 + lr;
    const unsigned short* ar = xm2 + (size_t)row*DINNER;
    float acc = bias[n];
    #pragma unroll 4
    for (int k2 = 0; k2 < DINNER; k2 += 2){
        unsigned int u = *(const unsigned int*)(ar + k2);
        acc += b2f(u & 0xffff)*w[k2*32 + n] + b2f(u >> 16)*w[(k2+1)*32 + n];
    }
    xdbl[(size_t)row*32 + n] = acc;
}

// ---------------- sequential scan: LDS weights, rotating reg prefetch ------
// h_{t+1}[i] = tanh(sum_j exp(dtp*A[i][j]) h_t[j]) + b_t[i]*h_t[i] + c_t[i]
__device__ __forceinline__ float scan_step_flat(float h, const float (&W)[16],
                                                float bv, float cv)
{
    float r1  = dppf<0x121>(h);
    float r2  = dppf<0x122>(h);
    float r3  = dppf<0x123>(h);
    float r4  = dppf<0x124>(h);
    float r5  = dppf<0x125>(h);
    float r6  = dppf<0x126>(h);
    float r7  = dppf<0x127>(h);
    float r8  = dppf<0x128>(h);
    float r9  = dppf<0x129>(h);
    float r10 = dppf<0x12a>(h);
    float r11 = dppf<0x12b>(h);
    float r12 = dppf<0x12c>(h);
    float r13 = dppf<0x12d>(h);
    float r14 = dppf<0x12e>(h);
    float r15 = dppf<0x12f>(h);
    float a0 = W[0]*h;    a0 = fmaf(W[1], r1, a0);  a0 = fmaf(W[2], r2, a0);  a0 = fmaf(W[3], r3, a0);
    float a1 = W[4]*r4;   a1 = fmaf(W[5], r5, a1);  a1 = fmaf(W[6], r6, a1);  a1 = fmaf(W[7], r7, a1);
    float a2 = W[8]*r8;   a2 = fmaf(W[9], r9, a2);  a2 = fmaf(W[10],r10,a2);  a2 = fmaf(W[11],r11,a2);
    float a3 = W[12]*r12; a3 = fmaf(W[13],r13,a3);  a3 = fmaf(W[14],r14,a3);  a3 = fmaf(W[15],r15,a3);
    float s = (a0+a1)+(a2+a3);
    float e2 = __expf(2.f*s);
    float th = 1.f - 2.f*__builtin_amdgcn_rcpf(e2 + 1.f);
    return th + fmaf(bv, h, cv);
}

__device__ __forceinline__ void loadW16(float (&W)[16], const float* row){
    const float4* r4 = (const float4*)row;
    float4 w0=r4[0], w1=r4[1], w2=r4[2], w3=r4[3];
    W[0]=w0.x; W[1]=w0.y; W[2]=w0.z; W[3]=w0.w;
    W[4]=w1.x; W[5]=w1.y; W[6]=w1.z; W[7]=w1.w;
    W[8]=w2.x; W[9]=w2.y; W[10]=w2.z; W[11]=w2.w;
    W[12]=w3.x; W[13]=w3.y; W[14]=w3.z; W[15]=w3.w;
}

__global__ __launch_bounds__(128,1) void scan_k(
    const float* __restrict__ xdbl, const float* __restrict__ dt,
    const float* __restrict__ A, float* __restrict__ hs)
{
    __shared__ float Wl[16*16*20];      // row (p*16+i), stride 20 floats (80B)
    __shared__ float bc[2][2][64*32];   // [wave][buf][step*32 + {b:0..15,c:16..31}]
    int tid = threadIdx.x;
    int wv = tid >> 6, lane = tid & 63;
    int i = lane & 15;
    int b = wv;

    // probe: identical DPP fan applied to lane index -> source-lane order
    int c[16];
    c[0]  = i;
    c[1]  = dppi<0x121>(i);
    c[2]  = dppi<0x122>(i);
    c[3]  = dppi<0x123>(i);
    c[4]  = dppi<0x124>(i);
    c[5]  = dppi<0x125>(i);
    c[6]  = dppi<0x126>(i);
    c[7]  = dppi<0x127>(i);
    c[8]  = dppi<0x128>(i);
    c[9]  = dppi<0x129>(i);
    c[10] = dppi<0x12a>(i);
    c[11] = dppi<0x12b>(i);
    c[12] = dppi<0x12c>(i);
    c[13] = dppi<0x12d>(i);
    c[14] = dppi<0x12e>(i);
    c[15] = dppi<0x12f>(i);

    // fill Wl: 128 threads cover 256 rows in 2 passes
    #pragma unroll
    for (int pp=0; pp<2; ++pp){
        int p = pp*8 + (tid >> 4);
        float dtp = __expf(dt[p]);
        #pragma unroll
        for (int j=0;j<16;++j)
            Wl[(p*16 + i)*20 + j] = __expf(dtp * A[i*16 + c[j]]);
    }
    // stage chunk 0 (one-time direct staging)
    {
        const float4* src = (const float4*)(xdbl + (size_t)(b*SEQ)*32);
        float4* dst = (float4*)&bc[wv][0][0];
        #pragma unroll
        for (int t=0;t<8;++t) dst[lane + t*64] = src[lane + t*64];
    }
    __syncthreads();   // Wl is written cross-wave; once only

    float Wb[4][16];
    #pragma unroll
    for (int q=0;q<4;++q) loadW16(Wb[q], &Wl[(q*16+i)*20]);

    float hn = 0.f;
    for (int chunk = 0; chunk < 32; ++chunk){
        float4 stg[8];
        bool more = (chunk < 31);
        if (more){
            const float4* nsrc = (const float4*)(xdbl + (size_t)(b*SEQ + (chunk+1)*64)*32);
            #pragma unroll
            for (int t=0;t<8;++t) stg[t] = nsrc[lane + t*64];   // fire global loads
        }
        const float* cur = &bc[wv][chunk&1][0];
        float bv = cur[i], cv = cur[16 + i];
        size_t hbase = (size_t)(b*SEQ + chunk*64)*16 + i;
        #pragma unroll 1
        for (int s16=0; s16<4; ++s16){
            #pragma unroll
            for (int p=0; p<16; ++p){
                int st  = s16*16 + p;
                int stn = (st+1) & 63;
                float bvn = cur[stn*32 + i];        // b/c prefetch, 1 step ahead
                float cvn = cur[stn*32 + 16 + i];
                hn = scan_step_flat(hn, Wb[p&3], bv, cv);
                if (lane < 16) hs[hbase + (size_t)st*16] = hn;
                loadW16(Wb[p&3], &Wl[(((p+4)&15)*16 + i)*20]);  // distance-4 prefetch
                bv = bvn; cv = cvn;
            }
        }
        if (more){   // vmcnt long satisfied by 64 steps of compute
            float4* nb = (float4*)&bc[wv][(chunk+1)&1][0];
            #pragma unroll
            for (int t=0;t<8;++t) nb[lane + t*64] = stg[t];
        }
    }
}

// ---------------- y = repeat(hs,128) + res (bf16) --------------------------
__global__ __launch_bounds__(256) void y_assemble(
    const float* __restrict__ hs, const unsigned short* __restrict__ xr,
    unsigned short* __restrict__ y)
{
    int idx = blockIdx.x*256 + threadIdx.x;
    int r = idx >> 10;
    int c2 = (idx & 1023)*2;
    unsigned int u = *(const unsigned int*)(xr + (size_t)r*DFF + DINNER + c2);
    float h0 = hs[(size_t)r*16 + (c2 >> 7)];
    float y0 = h0 + b2f(u & 0xffff);
    float y1 = h0 + b2f(u >> 16);
    *(unsigned int*)(y + (size_t)r*DINNER + c2) =
        (unsigned int)f2b(y0) | ((unsigned int)f2b(y1) << 16);
}

// ---------------------------------------------------------------------------
extern "C" void kernel_launch(void* const* d_in, const int* in_sizes, int n_in,
                              void* d_out, int out_size, void* d_ws, size_t ws_size,
                              hipStream_t stream)
{
    (void)in_sizes; (void)n_in; (void)out_size; (void)ws_size;
    const float* x     = (const float*)d_in[0];
    const float* ln1_g = (const float*)d_in[1];
    const float* ln1_b = (const float*)d_in[2];
    const float* Wq    = (const float*)d_in[3];
    const float* bq    = (const float*)d_in[4];
    const float* Wk    = (const float*)d_in[5];
    const float* bk    = (const float*)d_in[6];
    const float* Wv    = (const float*)d_in[7];
    const float* bv    = (const float*)d_in[8];
    const float* Wo    = (const float*)d_in[9];
    const float* bo    = (const float*)d_in[10];
    const float* ln2_g = (const float*)d_in[11];
    const float* ln2_b = (const float*)d_in[12];
    const float* in_w  = (const float*)d_in[13];
    const float* in_b  = (const float*)d_in[14];
    const float* conv_w= (const float*)d_in[15];
    const float* conv_b= (const float*)d_in[16];
    const float* xp_w  = (const float*)d_in[17];
    const float* xp_b  = (const float*)d_in[18];
    const float* dt    = (const float*)d_in[19];
    const float* A     = (const float*)d_in[20];
    const float* out_w = (const float*)d_in[22];
    const float* out_b = (const float*)d_in[23];
    const float* ln3_g = (const float*)d_in[24];
    const float* ln3_b = (const float*)d_in[25];
    const float* fc1_w = (const float*)d_in[26];
    const float* fc1_b = (const float*)d_in[27];
    const float* fc2_w = (const float*)d_in[28];
    const float* fc2_b = (const float*)d_in[29];

    char* ws = (char*)d_ws;
    const size_t MB = 1ull << 20;
    unsigned short* qkvT = (unsigned short*)(ws + 0*MB);   // WqT|WkT|WvT, 6MB
    unsigned short* WoT  = (unsigned short*)(ws + 6*MB);
    unsigned short* inT  = (unsigned short*)(ws + 8*MB);
    unsigned short* outT = (unsigned short*)(ws + 16*MB);
    unsigned short* f1T  = (unsigned short*)(ws + 20*MB);
    unsigned short* f2T  = (unsigned short*)(ws + 28*MB);
    unsigned short* hbf  = (unsigned short*)(ws + 36*MB);
    float*          x2   = (float*)(ws + 44*MB);
    float*          x3   = (float*)(ws + 60*MB);
    unsigned short* qkv  = (unsigned short*)(ws + 76*MB);  // 24MB fused QKV
    unsigned short* attnb= (unsigned short*)(ws + 100*MB);
    unsigned short* xr   = (unsigned short*)(ws + 76*MB);  // reuse after attn
    unsigned short* ffn  = (unsigned short*)(ws + 76*MB);  // reuse after y
    unsigned short* xm2  = (unsigned short*)(ws + 108*MB);
    unsigned short* yb   = (unsigned short*)(ws + 108*MB); // reuse after xp
    float*          xdbl = (float*)(ws + 124*MB);
    float*          hsb  = (float*)(ws + 124*MB + 512*1024);
    float*          bqkv = (float*)(ws + 125*MB);

    dim3 blk(256);
    transpose_cast<<<dim3(16,16), blk, 0, stream>>>(Wq, qkvT,              1024, 1024);
    transpose_cast<<<dim3(16,16), blk, 0, stream>>>(Wk, qkvT + 1024*1024,  1024, 1024);
    transpose_cast<<<dim3(16,16), blk, 0, stream>>>(Wv, qkvT + 2*1024*1024,1024, 1024);
    transpose_cast<<<dim3(16,16), blk, 0, stream>>>(Wo, WoT, 1024, 1024);
    transpose_cast<<<dim3(64,16), blk, 0, stream>>>(in_w, inT, 1024, 4096);
    transpose_cast<<<dim3(16,32), blk, 0, stream>>>(out_w, outT, 2048, 1024);
    transpose_cast<<<dim3(64,16), blk, 0, stream>>>(fc1_w, f1T, 1024, 4096);
    transpose_cast<<<dim3(16,64), blk, 0, stream>>>(fc2_w, f2T, 4096, 1024);
    concat_bias<<<12, blk, 0, stream>>>(bq, bk, bv, bqkv);

    layernorm_bf16<<<MROWS, blk, 0, stream>>>(x, ln1_g, ln1_b, hbf);
    gemm_bt<1,0,0><<<dim3(24,32), blk, 0, stream>>>(hbf, qkvT, bqkv, nullptr, qkv, QKVLD, 1024);
    attn_flash<<<dim3(32,32), blk, 0, stream>>>(qkv, attnb);
    gemm_bt<0,1,0><<<dim3(8,32),  blk, 0, stream>>>(attnb, WoT, bo, x, x2, 1024, 1024);
    layernorm_bf16<<<MROWS, blk, 0, stream>>>(x2, ln2_g, ln2_b, hbf);
    gemm_bt<1,0,0><<<dim3(32,32), blk, 0, stream>>>(hbf, inT, in_b, nullptr, xr, 4096, 1024);
    conv_silu<<<16384, blk, 0, stream>>>(xr, conv_w, conv_b, xm2);
    xp_gemm<<<512, blk, 0, stream>>>(xm2, xp_w, xp_b, xdbl);
    scan_k<<<1, dim3(128), 0, stream>>>(xdbl, dt, A, hsb);
    y_assemble<<<16384, blk, 0, stream>>>(hsb, xr, yb);
    gemm_bt<0,1,0><<<dim3(8,32),  blk, 0, stream>>>(yb, outT, out_b, x2, x3, 1024, 2048);
    layernorm_bf16<<<MROWS, blk, 0, stream>>>(x3, ln3_g, ln3_b, hbf);
    gemm_bt<1,0,1><<<dim3(32,32), blk, 0, stream>>>(hbf, f1T, fc1_b, nullptr, ffn, 4096, 1024);
    gemm_bt<0,1,0><<<dim3(8,32),  blk, 0, stream>>>(ffn, f2T, fc2_b, x3, (float*)d_out, 1024, 4096);
}

// Round 5
// 1048.405 us; speedup vs baseline: 1.1081x; 1.1081x over previous
//
#include <hip/hip_runtime.h>
#include <hip/hip_bf16.h>

// ---------------------------------------------------------------------------
// R5 changes vs R4:
//  * scan_k: weights REGISTER-RESIDENT as packed bf16 pairs (16 phases x 8
//    uints = 128 VGPRs; R3 proved 256 f32 regs spills, R2/R3/R4 proved any
//    memory fetch on the serial path costs ~200 cyc/step). Unpack = 1 VALU op
//    per weight, no memory dependence. Weights pre-scaled by 2.0 (folds the
//    tanh 2*s mul). bc staged via global_load_lds double-buffer (no stg regs,
//    no LDS-write pass), explicit s_waitcnt vmcnt(0) at chunk end; bc reads
//    2-step prefetch; NO barriers in the whole kernel.
//  Everything else identical to R4.
// ---------------------------------------------------------------------------

#define SEQ     2048
#define BATCH   2
#define MROWS   4096      // BATCH*SEQ
#define DMODEL  1024
#define DINNER  2048
#define DFF     4096
#define QKVLD   3072

typedef __attribute__((ext_vector_type(8))) short bf16x8;
typedef __attribute__((ext_vector_type(4))) float f32x4;

__device__ __forceinline__ unsigned short f2b(float x){
    __hip_bfloat16 h = __float2bfloat16(x);
    return *reinterpret_cast<unsigned short*>(&h);
}
__device__ __forceinline__ float b2f(unsigned short u){
    __hip_bfloat16 h;
    *reinterpret_cast<unsigned short*>(&h) = u;
    return __bfloat162float(h);
}
__device__ __forceinline__ float b2f_lo(unsigned u){
    return __builtin_bit_cast(float, u << 16);
}
__device__ __forceinline__ float b2f_hi(unsigned u){
    return __builtin_bit_cast(float, u & 0xFFFF0000u);
}
__device__ __forceinline__ float gelu_f(float v){
    float u = 0.7978845608f*(v + 0.044715f*v*v*v);
    float e = __expf(2.f*u);
    float th = 1.f - 2.f*__builtin_amdgcn_rcpf(e + 1.f);
    return 0.5f*v*(1.f + th);
}
__device__ __forceinline__ void gload16(const unsigned short* g, unsigned short* l){
    __builtin_amdgcn_global_load_lds(
        (const __attribute__((address_space(1))) void*)g,
        (__attribute__((address_space(3))) void*)l, 16, 0, 0);
}
__device__ __forceinline__ void gload16f(const float* g, float* l){
    __builtin_amdgcn_global_load_lds(
        (const __attribute__((address_space(1))) void*)g,
        (__attribute__((address_space(3))) void*)l, 16, 0, 0);
}
template<int CTRL>
__device__ __forceinline__ float dppf(float x){
    int r = __builtin_amdgcn_mov_dpp(__builtin_bit_cast(int, x), CTRL, 0xf, 0xf, false);
    return __builtin_bit_cast(float, r);
}
template<int CTRL>
__device__ __forceinline__ int dppi(int x){
    return __builtin_amdgcn_mov_dpp(x, CTRL, 0xf, 0xf, false);
}

// ---------------- transpose + cast: W (KxN f32) -> Wt (NxK bf16) ----------
__global__ __launch_bounds__(256) void transpose_cast(
    const float* __restrict__ W, unsigned short* __restrict__ Wt, int K, int N)
{
    __shared__ float t[64*65];
    int n0 = blockIdx.x*64, k0 = blockIdx.y*64;
    int c = threadIdx.x & 63, r0 = threadIdx.x >> 6;
    #pragma unroll
    for (int rr = 0; rr < 64; rr += 4)
        t[(rr+r0)*65 + c] = W[(size_t)(k0+rr+r0)*N + n0 + c];
    __syncthreads();
    #pragma unroll
    for (int rr = 0; rr < 64; rr += 4)
        Wt[(size_t)(n0+rr+r0)*K + k0 + c] = f2b(t[c*65 + rr + r0]);
}

// ---------------- concat 3 bias vectors --------------------------------
__global__ __launch_bounds__(256) void concat_bias(
    const float* __restrict__ b0, const float* __restrict__ b1,
    const float* __restrict__ b2, float* __restrict__ o)
{
    int t = blockIdx.x*256 + threadIdx.x;
    float v = (t < 1024) ? b0[t] : (t < 2048 ? b1[t-1024] : b2[t-2048]);
    o[t] = v;
}

// ---------------- layernorm row=1024, f32 in -> bf16 out ------------------
__global__ __launch_bounds__(256) void layernorm_bf16(
    const float* __restrict__ x, const float* __restrict__ g,
    const float* __restrict__ b, unsigned short* __restrict__ out)
{
    int row = blockIdx.x;
    const float4* xr = (const float4*)(x + (size_t)row*DMODEL);
    int tid = threadIdx.x;
    float4 xv = xr[tid];
    float s  = xv.x + xv.y + xv.z + xv.w;
    float ss = xv.x*xv.x + xv.y*xv.y + xv.z*xv.z + xv.w*xv.w;
    #pragma unroll
    for (int d = 32; d > 0; d >>= 1){ s += __shfl_xor(s,d); ss += __shfl_xor(ss,d); }
    __shared__ float sm[8];
    int wv = tid>>6, ln = tid&63;
    if (ln == 0){ sm[wv] = s; sm[4+wv] = ss; }
    __syncthreads();
    s  = sm[0]+sm[1]+sm[2]+sm[3];
    ss = sm[4]+sm[5]+sm[6]+sm[7];
    float mean = s*(1.f/DMODEL);
    float var  = ss*(1.f/DMODEL) - mean*mean;
    float rstd = rsqrtf(var + 1e-5f);
    float4 gv = ((const float4*)g)[tid];
    float4 bv = ((const float4*)b)[tid];
    ushort4 o;
    o.x = f2b((xv.x-mean)*rstd*gv.x + bv.x);
    o.y = f2b((xv.y-mean)*rstd*gv.y + bv.y);
    o.z = f2b((xv.z-mean)*rstd*gv.z + bv.z);
    o.w = f2b((xv.w-mean)*rstd*gv.w + bv.w);
    ((ushort4*)(out + (size_t)row*DMODEL))[tid] = o;
}

// ---------------- GEMM: C[M,N] = act(A[M,K] @ Bt[N,K]^T + bias) (+res) ----
// 128x128 tile, 4 waves, each 64x64. BK=64. global_load_lds staging (m97).
template<int OUT_BF16, int HAS_RES, int ACT>
__global__ __launch_bounds__(256,2) void gemm_bt(
    const unsigned short* __restrict__ A, const unsigned short* __restrict__ Bt,
    const float* __restrict__ bias, const float* __restrict__ res,
    void* __restrict__ outp, int Ndim, int Kdim)
{
    __shared__ unsigned short As[128*64];   // unpadded: required by global_load_lds
    __shared__ unsigned short Bs[128*64];
    int tid = threadIdx.x;
    int lane = tid & 63, wv = tid >> 6;
    int l15 = lane & 15, quad = lane >> 4;
    int m0 = blockIdx.y*128, n0 = blockIdx.x*128;
    int mo = (wv>>1)*64, no = (wv&1)*64;
    int rsub = (lane >> 3);          // 0..7
    int cc8  = (lane & 7)*8;         // element col within 64
    f32x4 zz = {0.f,0.f,0.f,0.f};
    f32x4 acc[4][4];
    #pragma unroll
    for (int i=0;i<4;++i)
      #pragma unroll
      for (int j=0;j<4;++j) acc[i][j] = zz;

    for (int k0 = 0; k0 < Kdim; k0 += 64){
        const unsigned short* Ab = A  + (size_t)(m0 + wv*32 + rsub)*Kdim + k0 + cc8;
        const unsigned short* Bb = Bt + (size_t)(n0 + wv*32 + rsub)*Kdim + k0 + cc8;
        #pragma unroll
        for (int i=0;i<4;++i){
            gload16(Ab + (size_t)(i*8)*Kdim, &As[(wv*32 + i*8)*64]);
            gload16(Bb + (size_t)(i*8)*Kdim, &Bs[(wv*32 + i*8)*64]);
        }
        __syncthreads();
        #pragma unroll
        for (int kc=0;kc<2;++kc){
            bf16x8 af[4], bfr[4];
            #pragma unroll
            for (int t=0;t<4;++t){
                af[t]  = *(const bf16x8*)(&As[(mo + t*16 + l15)*64 + kc*32 + quad*8]);
                bfr[t] = *(const bf16x8*)(&Bs[(no + t*16 + l15)*64 + kc*32 + quad*8]);
            }
            #pragma unroll
            for (int mt=0;mt<4;++mt)
              #pragma unroll
              for (int nt=0;nt<4;++nt)
                acc[mt][nt] = __builtin_amdgcn_mfma_f32_16x16x32_bf16(af[mt], bfr[nt], acc[mt][nt], 0,0,0);
        }
        __syncthreads();
    }
    #pragma unroll
    for (int mt=0;mt<4;++mt){
      #pragma unroll
      for (int nt=0;nt<4;++nt){
        int gn = n0 + no + nt*16 + l15;
        float bval = bias[gn];
        #pragma unroll
        for (int r=0;r<4;++r){
            int gm = m0 + mo + mt*16 + quad*4 + r;
            size_t off = (size_t)gm*Ndim + gn;
            float v = acc[mt][nt][r] + bval;
            if constexpr (HAS_RES) v += res[off];
            if constexpr (ACT == 1) v = gelu_f(v);
            if constexpr (OUT_BF16) ((unsigned short*)outp)[off] = f2b(v);
            else                    ((float*)outp)[off] = v;
        }
      }
    }
}

// ---------------- flash attention, causal, 16 heads of 64 ------------------
// q/k/v live in the fused qkv buffer with row stride QKVLD.
__global__ __launch_bounds__(256,2) void attn_flash(
    const unsigned short* __restrict__ qkv, unsigned short* __restrict__ attn)
{
    __shared__ unsigned short Qs[64*72];
    __shared__ unsigned short Ks[64*72];
    __shared__ unsigned short Vt[64*72];
    __shared__ unsigned short Ps[64*72];
    int bh = blockIdx.y;
    int qt = (int)gridDim.x - 1 - (int)blockIdx.x;
    int q0 = qt*64;
    int tid = threadIdx.x, wv = tid>>6, lane = tid&63;
    int l15 = lane&15, quad = lane>>4;
    const size_t basei = (size_t)(bh>>4)*SEQ*QKVLD + (size_t)(bh&15)*64;
    const unsigned short* q = qkv + basei;
    const unsigned short* k = qkv + basei + DMODEL;
    const unsigned short* v = qkv + basei + 2*DMODEL;
    const size_t baseo = (size_t)(bh>>4)*SEQ*DMODEL + (size_t)(bh&15)*64;

    #pragma unroll
    for (int i=0;i<2;++i){
        int cch = tid + i*256; int r = cch>>3, cc = cch&7;
        *(uint4*)(&Qs[r*72 + cc*8]) = *(const uint4*)(q + (size_t)(q0+r)*QKVLD + cc*8);
    }
    __syncthreads();
    bf16x8 aq0 = *(const bf16x8*)(&Qs[(wv*16 + l15)*72 + quad*8]);
    bf16x8 aq1 = *(const bf16x8*)(&Qs[(wv*16 + l15)*72 + 32 + quad*8]);

    float m_i[4], l_i[4];
    f32x4 zz = {0.f,0.f,0.f,0.f};
    f32x4 o[4];
    #pragma unroll
    for (int r=0;r<4;++r){ m_i[r] = -__builtin_inff(); l_i[r] = 0.f; }
    #pragma unroll
    for (int d=0;d<4;++d) o[d] = zz;

    for (int kt = 0; kt <= qt; ++kt){
        int t0 = kt*64;
        #pragma unroll
        for (int i=0;i<2;++i){
            int cch = tid + i*256; int r = cch>>3, cc = cch&7;
            *(uint4*)(&Ks[r*72 + cc*8]) = *(const uint4*)(k + (size_t)(t0+r)*QKVLD + cc*8);
            uint4 vv = *(const uint4*)(v + (size_t)(t0+r)*QKVLD + cc*8);
            const unsigned short* pv = (const unsigned short*)&vv;
            #pragma unroll
            for (int j=0;j<8;++j) Vt[(cc*8+j)*72 + r] = pv[j];
        }
        __syncthreads();

        f32x4 sc[4];
        #pragma unroll
        for (int st=0;st<4;++st){
            bf16x8 b0 = *(const bf16x8*)(&Ks[(st*16+l15)*72 + quad*8]);
            bf16x8 b1 = *(const bf16x8*)(&Ks[(st*16+l15)*72 + 32 + quad*8]);
            sc[st] = __builtin_amdgcn_mfma_f32_16x16x32_bf16(aq0, b0, zz, 0,0,0);
            sc[st] = __builtin_amdgcn_mfma_f32_16x16x32_bf16(aq1, b1, sc[st], 0,0,0);
        }
        bool diag = (kt == qt);
        float sval[4][4];
        float mrow[4];
        #pragma unroll
        for (int r=0;r<4;++r) mrow[r] = -__builtin_inff();
        #pragma unroll
        for (int st=0;st<4;++st)
          #pragma unroll
          for (int r=0;r<4;++r){
            float svv = sc[st][r]*0.125f;
            if (diag && (st*16 + l15 > wv*16 + quad*4 + r)) svv = -__builtin_inff();
            sval[st][r] = svv;
            mrow[r] = fmaxf(mrow[r], svv);
          }
        #pragma unroll
        for (int d=1; d<16; d<<=1)
          #pragma unroll
          for (int r=0;r<4;++r) mrow[r] = fmaxf(mrow[r], __shfl_xor(mrow[r], d));
        float alpha[4], rsum[4];
        #pragma unroll
        for (int r=0;r<4;++r){
            float mn = fmaxf(m_i[r], mrow[r]);
            alpha[r] = __expf(m_i[r] - mn);
            m_i[r] = mn;
        }
        #pragma unroll
        for (int st=0;st<4;++st)
          #pragma unroll
          for (int r=0;r<4;++r) sval[st][r] = __expf(sval[st][r] - m_i[r]);
        #pragma unroll
        for (int r=0;r<4;++r) rsum[r] = sval[0][r]+sval[1][r]+sval[2][r]+sval[3][r];
        #pragma unroll
        for (int d=1; d<16; d<<=1)
          #pragma unroll
          for (int r=0;r<4;++r) rsum[r] += __shfl_xor(rsum[r], d);
        #pragma unroll
        for (int r=0;r<4;++r) l_i[r] = l_i[r]*alpha[r] + rsum[r];
        #pragma unroll
        for (int st=0;st<4;++st)
          #pragma unroll
          for (int r=0;r<4;++r)
            Ps[(wv*16 + quad*4 + r)*72 + st*16 + l15] = f2b(sval[st][r]);
        #pragma unroll
        for (int d=0;d<4;++d)
          #pragma unroll
          for (int r=0;r<4;++r) o[d][r] = o[d][r]*alpha[r];
        __syncthreads();
        bf16x8 ap0 = *(const bf16x8*)(&Ps[(wv*16 + l15)*72 + quad*8]);
        bf16x8 ap1 = *(const bf16x8*)(&Ps[(wv*16 + l15)*72 + 32 + quad*8]);
        #pragma unroll
        for (int dtile=0;dtile<4;++dtile){
            bf16x8 b0 = *(const bf16x8*)(&Vt[(dtile*16+l15)*72 + quad*8]);
            bf16x8 b1 = *(const bf16x8*)(&Vt[(dtile*16+l15)*72 + 32 + quad*8]);
            o[dtile] = __builtin_amdgcn_mfma_f32_16x16x32_bf16(ap0, b0, o[dtile], 0,0,0);
            o[dtile] = __builtin_amdgcn_mfma_f32_16x16x32_bf16(ap1, b1, o[dtile], 0,0,0);
        }
        __syncthreads();
    }
    #pragma unroll
    for (int r=0;r<4;++r){
        float inv = 1.f/l_i[r];
        int gm = q0 + wv*16 + quad*4 + r;
        #pragma unroll
        for (int dtile=0;dtile<4;++dtile)
            attn[baseo + (size_t)gm*DMODEL + dtile*16 + l15] = f2b(o[dtile][r]*inv);
    }
}

// ---------------- depthwise causal conv(4) + bias + silu -------------------
__global__ __launch_bounds__(256) void conv_silu(
    const unsigned short* __restrict__ xr, const float* __restrict__ cw,
    const float* __restrict__ cb, unsigned short* __restrict__ xm2)
{
    int idx = blockIdx.x*256 + threadIdx.x;
    int r  = idx >> 10;
    int c2 = (idx & 1023)*2;
    int s  = r & (SEQ-1);
    float4 w0 = *(const float4*)(cw + c2*4);
    float4 w1 = *(const float4*)(cw + (c2+1)*4);
    float w0a[4] = {w0.x,w0.y,w0.z,w0.w};
    float w1a[4] = {w1.x,w1.y,w1.z,w1.w};
    float a0 = cb[c2], a1 = cb[c2+1];
    const unsigned short* xrow = xr + (size_t)r*DFF + c2;
    #pragma unroll
    for (int j=0;j<4;++j){
        int sp = s - 3 + j;
        if (sp >= 0){
            int off = (j-3)*DFF;
            unsigned int u = *(const unsigned int*)(xrow + off);
            a0 += w0a[j]*b2f(u & 0xffff);
            a1 += w1a[j]*b2f(u >> 16);
        }
    }
    float s0 = a0 * __builtin_amdgcn_rcpf(1.f + __expf(-a0));
    float s1 = a1 * __builtin_amdgcn_rcpf(1.f + __expf(-a1));
    unsigned int op = (unsigned int)f2b(s0) | ((unsigned int)f2b(s1) << 16);
    *(unsigned int*)(xm2 + (size_t)r*DINNER + c2) = op;
}

// ---------------- xdbl = xm2 @ xp_w + xp_b  (N=32, K=2048) -----------------
__global__ __launch_bounds__(256) void xp_gemm(
    const unsigned short* __restrict__ xm2, const float* __restrict__ w,
    const float* __restrict__ bias, float* __restrict__ xdbl)
{
    int tid = threadIdx.x;
    int lr = tid >> 5, n = tid & 31;
    int row = blockIdx.x*8 + lr;
    const unsigned short* ar = xm2 + (size_t)row*DINNER;
    float acc = bias[n];
    #pragma unroll 4
    for (int k2 = 0; k2 < DINNER; k2 += 2){
        unsigned int u = *(const unsigned int*)(ar + k2);
        acc += b2f(u & 0xffff)*w[k2*32 + n] + b2f(u >> 16)*w[(k2+1)*32 + n];
    }
    xdbl[(size_t)row*32 + n] = acc;
}

// ---------------- sequential scan: packed-bf16 register weights ------------
// h_{t+1}[i] = tanh(sum_j exp(dtp*A[i][j]) h_t[j]) + b_t[i]*h_t[i] + c_t[i]
// Weights pre-scaled by 2.0: x = sum (2W) h, tanh = 1 - 2/(e^x + 1).
__device__ __forceinline__ float scan_step_pk(float h, const unsigned (&Wp)[8],
                                              float bv, float cv)
{
    float r1  = dppf<0x121>(h);
    float r2  = dppf<0x122>(h);
    float r3  = dppf<0x123>(h);
    float r4  = dppf<0x124>(h);
    float r5  = dppf<0x125>(h);
    float r6  = dppf<0x126>(h);
    float r7  = dppf<0x127>(h);
    float r8  = dppf<0x128>(h);
    float r9  = dppf<0x129>(h);
    float r10 = dppf<0x12a>(h);
    float r11 = dppf<0x12b>(h);
    float r12 = dppf<0x12c>(h);
    float r13 = dppf<0x12d>(h);
    float r14 = dppf<0x12e>(h);
    float r15 = dppf<0x12f>(h);
    float a0 = b2f_lo(Wp[0])*h;
    a0 = fmaf(b2f_hi(Wp[0]), r1, a0);
    a0 = fmaf(b2f_lo(Wp[1]), r2, a0);
    a0 = fmaf(b2f_hi(Wp[1]), r3, a0);
    float a1 = b2f_lo(Wp[2])*r4;
    a1 = fmaf(b2f_hi(Wp[2]), r5, a1);
    a1 = fmaf(b2f_lo(Wp[3]), r6, a1);
    a1 = fmaf(b2f_hi(Wp[3]), r7, a1);
    float a2 = b2f_lo(Wp[4])*r8;
    a2 = fmaf(b2f_hi(Wp[4]), r9, a2);
    a2 = fmaf(b2f_lo(Wp[5]), r10, a2);
    a2 = fmaf(b2f_hi(Wp[5]), r11, a2);
    float a3 = b2f_lo(Wp[6])*r12;
    a3 = fmaf(b2f_hi(Wp[6]), r13, a3);
    a3 = fmaf(b2f_lo(Wp[7]), r14, a3);
    a3 = fmaf(b2f_hi(Wp[7]), r15, a3);
    float x = (a0+a1)+(a2+a3);              // = 2*s (weights pre-scaled)
    float e2 = __expf(x);
    float th = 1.f - 2.f*__builtin_amdgcn_rcpf(e2 + 1.f);
    return th + fmaf(bv, h, cv);
}

__global__ __launch_bounds__(128,1) void scan_k(
    const float* __restrict__ xdbl, const float* __restrict__ dt,
    const float* __restrict__ A, float* __restrict__ hs)
{
    __shared__ float bc[2][2][64*32];   // [wave][buf][step*32 + {b:0..15,c:16..31}]
    int tid = threadIdx.x;
    int wv = tid >> 6, lane = tid & 63;
    int i = lane & 15;
    int b = wv;

    // probe: identical DPP fan applied to lane index -> source-lane order
    int c[16];
    c[0]  = i;
    c[1]  = dppi<0x121>(i);
    c[2]  = dppi<0x122>(i);
    c[3]  = dppi<0x123>(i);
    c[4]  = dppi<0x124>(i);
    c[5]  = dppi<0x125>(i);
    c[6]  = dppi<0x126>(i);
    c[7]  = dppi<0x127>(i);
    c[8]  = dppi<0x128>(i);
    c[9]  = dppi<0x129>(i);
    c[10] = dppi<0x12a>(i);
    c[11] = dppi<0x12b>(i);
    c[12] = dppi<0x12c>(i);
    c[13] = dppi<0x12d>(i);
    c[14] = dppi<0x12e>(i);
    c[15] = dppi<0x12f>(i);

    // packed-bf16 weight table: 16 phases x 8 uints = 128 VGPRs
    unsigned Wpk[16][8];
    #pragma unroll
    for (int p=0;p<16;++p){
        float dtp = __expf(dt[p]);
        #pragma unroll
        for (int jj=0;jj<8;++jj){
            float w0 = 2.f*__expf(dtp * A[i*16 + c[2*jj]]);
            float w1 = 2.f*__expf(dtp * A[i*16 + c[2*jj+1]]);
            Wpk[p][jj] = (unsigned)f2b(w0) | ((unsigned)f2b(w1) << 16);
        }
    }

    // stage chunk 0 via global_load_lds (8KB per wave)
    {
        const float* src = xdbl + (size_t)(b*SEQ)*32 + lane*4;
        #pragma unroll
        for (int k=0;k<8;++k)
            gload16f(src + k*256, &bc[wv][0][k*256]);
    }
    __builtin_amdgcn_s_waitcnt(0x0F70);   // vmcnt(0)

    float hn = 0.f;
    for (int chunk = 0; chunk < 32; ++chunk){
        if (chunk < 31){   // stage next chunk into the other buffer
            const float* nsrc = xdbl + (size_t)(b*SEQ + (chunk+1)*64)*32 + lane*4;
            float* nb = &bc[wv][(chunk+1)&1][0];
            #pragma unroll
            for (int k=0;k<8;++k)
                gload16f(nsrc + k*256, nb + k*256);
        }
        const float* cur = &bc[wv][chunk&1][0];
        float bv0 = cur[i],        cv0 = cur[16 + i];
        float bv1 = cur[32 + i],   cv1 = cur[48 + i];
        size_t hbase = (size_t)(b*SEQ + chunk*64)*16 + i;
        #pragma unroll 1
        for (int s16=0; s16<4; ++s16){
            #pragma unroll
            for (int p=0; p<16; ++p){
                int st  = s16*16 + p;
                hn = scan_step_pk(hn, Wpk[p], bv0, cv0);
                if (lane < 16) hs[hbase + (size_t)st*16] = hn;
                bv0 = bv1; cv0 = cv1;
                int stn = (st+2) & 63;
                bv1 = cur[stn*32 + i];        // 2-step bc prefetch
                cv1 = cur[stn*32 + 16 + i];
            }
        }
        __builtin_amdgcn_s_waitcnt(0x0F70);   // vmcnt(0): next buffer staged
    }
}

// ---------------- y = repeat(hs,128) + res (bf16) --------------------------
__global__ __launch_bounds__(256) void y_assemble(
    const float* __restrict__ hs, const unsigned short* __restrict__ xr,
    unsigned short* __restrict__ y)
{
    int idx = blockIdx.x*256 + threadIdx.x;
    int r = idx >> 10;
    int c2 = (idx & 1023)*2;
    unsigned int u = *(const unsigned int*)(xr + (size_t)r*DFF + DINNER + c2);
    float h0 = hs[(size_t)r*16 + (c2 >> 7)];
    float y0 = h0 + b2f(u & 0xffff);
    float y1 = h0 + b2f(u >> 16);
    *(unsigned int*)(y + (size_t)r*DINNER + c2) =
        (unsigned int)f2b(y0) | ((unsigned int)f2b(y1) << 16);
}

// ---------------------------------------------------------------------------
extern "C" void kernel_launch(void* const* d_in, const int* in_sizes, int n_in,
                              void* d_out, int out_size, void* d_ws, size_t ws_size,
                              hipStream_t stream)
{
    (void)in_sizes; (void)n_in; (void)out_size; (void)ws_size;
    const float* x     = (const float*)d_in[0];
    const float* ln1_g = (const float*)d_in[1];
    const float* ln1_b = (const float*)d_in[2];
    const float* Wq    = (const float*)d_in[3];
    const float* bq    = (const float*)d_in[4];
    const float* Wk    = (const float*)d_in[5];
    const float* bk    = (const float*)d_in[6];
    const float* Wv    = (const float*)d_in[7];
    const float* bv    = (const float*)d_in[8];
    const float* Wo    = (const float*)d_in[9];
    const float* bo    = (const float*)d_in[10];
    const float* ln2_g = (const float*)d_in[11];
    const float* ln2_b = (const float*)d_in[12];
    const float* in_w  = (const float*)d_in[13];
    const float* in_b  = (const float*)d_in[14];
    const float* conv_w= (const float*)d_in[15];
    const float* conv_b= (const float*)d_in[16];
    const float* xp_w  = (const float*)d_in[17];
    const float* xp_b  = (const float*)d_in[18];
    const float* dt    = (const float*)d_in[19];
    const float* A     = (const float*)d_in[20];
    const float* out_w = (const float*)d_in[22];
    const float* out_b = (const float*)d_in[23];
    const float* ln3_g = (const float*)d_in[24];
    const float* ln3_b = (const float*)d_in[25];
    const float* fc1_w = (const float*)d_in[26];
    const float* fc1_b = (const float*)d_in[27];
    const float* fc2_w = (const float*)d_in[28];
    const float* fc2_b = (const float*)d_in[29];

    char* ws = (char*)d_ws;
    const size_t MB = 1ull << 20;
    unsigned short* qkvT = (unsigned short*)(ws + 0*MB);   // WqT|WkT|WvT, 6MB
    unsigned short* WoT  = (unsigned short*)(ws + 6*MB);
    unsigned short* inT  = (unsigned short*)(ws + 8*MB);
    unsigned short* outT = (unsigned short*)(ws + 16*MB);
    unsigned short* f1T  = (unsigned short*)(ws + 20*MB);
    unsigned short* f2T  = (unsigned short*)(ws + 28*MB);
    unsigned short* hbf  = (unsigned short*)(ws + 36*MB);
    float*          x2   = (float*)(ws + 44*MB);
    float*          x3   = (float*)(ws + 60*MB);
    unsigned short* qkv  = (unsigned short*)(ws + 76*MB);  // 24MB fused QKV
    unsigned short* attnb= (unsigned short*)(ws + 100*MB);
    unsigned short* xr   = (unsigned short*)(ws + 76*MB);  // reuse after attn
    unsigned short* ffn  = (unsigned short*)(ws + 76*MB);  // reuse after y
    unsigned short* xm2  = (unsigned short*)(ws + 108*MB);
    unsigned short* yb   = (unsigned short*)(ws + 108*MB); // reuse after xp
    float*          xdbl = (float*)(ws + 124*MB);
    float*          hsb  = (float*)(ws + 124*MB + 512*1024);
    float*          bqkv = (float*)(ws + 125*MB);

    dim3 blk(256);
    transpose_cast<<<dim3(16,16), blk, 0, stream>>>(Wq, qkvT,              1024, 1024);
    transpose_cast<<<dim3(16,16), blk, 0, stream>>>(Wk, qkvT + 1024*1024,  1024, 1024);
    transpose_cast<<<dim3(16,16), blk, 0, stream>>>(Wv, qkvT + 2*1024*1024,1024, 1024);
    transpose_cast<<<dim3(16,16), blk, 0, stream>>>(Wo, WoT, 1024, 1024);
    transpose_cast<<<dim3(64,16), blk, 0, stream>>>(in_w, inT, 1024, 4096);
    transpose_cast<<<dim3(16,32), blk, 0, stream>>>(out_w, outT, 2048, 1024);
    transpose_cast<<<dim3(64,16), blk, 0, stream>>>(fc1_w, f1T, 1024, 4096);
    transpose_cast<<<dim3(16,64), blk, 0, stream>>>(fc2_w, f2T, 4096, 1024);
    concat_bias<<<12, blk, 0, stream>>>(bq, bk, bv, bqkv);

    layernorm_bf16<<<MROWS, blk, 0, stream>>>(x, ln1_g, ln1_b, hbf);
    gemm_bt<1,0,0><<<dim3(24,32), blk, 0, stream>>>(hbf, qkvT, bqkv, nullptr, qkv, QKVLD, 1024);
    attn_flash<<<dim3(32,32), blk, 0, stream>>>(qkv, attnb);
    gemm_bt<0,1,0><<<dim3(8,32),  blk, 0, stream>>>(attnb, WoT, bo, x, x2, 1024, 1024);
    layernorm_bf16<<<MROWS, blk, 0, stream>>>(x2, ln2_g, ln2_b, hbf);
    gemm_bt<1,0,0><<<dim3(32,32), blk, 0, stream>>>(hbf, inT, in_b, nullptr, xr, 4096, 1024);
    conv_silu<<<16384, blk, 0, stream>>>(xr, conv_w, conv_b, xm2);
    xp_gemm<<<512, blk, 0, stream>>>(xm2, xp_w, xp_b, xdbl);
    scan_k<<<1, dim3(128), 0, stream>>>(xdbl, dt, A, hsb);
    y_assemble<<<16384, blk, 0, stream>>>(hsb, xr, yb);
    gemm_bt<0,1,0><<<dim3(8,32),  blk, 0, stream>>>(yb, outT, out_b, x2, x3, 1024, 2048);
    layernorm_bf16<<<MROWS, blk, 0, stream>>>(x3, ln3_g, ln3_b, hbf);
    gemm_bt<1,0,1><<<dim3(32,32), blk, 0, stream>>>(hbf, f1T, fc1_b, nullptr, ffn, 4096, 1024);
    gemm_bt<0,1,0><<<dim3(8,32),  blk, 0, stream>>>(ffn, f2T, fc2_b, x3, (float*)d_out, 1024, 4096);
}

// Round 6
// 1015.920 us; speedup vs baseline: 1.1435x; 1.0320x over previous
//
#include <hip/hip_runtime.h>
#include <hip/hip_bf16.h>

// ---------------------------------------------------------------------------
// R6 changes vs R5 (scan shell-stripping; math core identical):
//  * scan_k: fully-unrolled 64-step chunk body (all LDS offsets immediate),
//    b/c packed as adjacent pairs -> 1 ds_read_b64/step (xp_gemm writes
//    interleaved), hs stores batched 4 steps -> 1 global_store_dwordx4 into
//    TRANSPOSED hsT[b][i][t] layout (y_assemble index updated).
//    R5 counters showed ~95 VALU instr/step (62% issue-busy): the serial
//    math is ~55; the rest was addressing/exec-toggle/copies -> removed.
// ---------------------------------------------------------------------------

#define SEQ     2048
#define BATCH   2
#define MROWS   4096      // BATCH*SEQ
#define DMODEL  1024
#define DINNER  2048
#define DFF     4096
#define QKVLD   3072

typedef __attribute__((ext_vector_type(8))) short bf16x8;
typedef __attribute__((ext_vector_type(4))) float f32x4;

__device__ __forceinline__ unsigned short f2b(float x){
    __hip_bfloat16 h = __float2bfloat16(x);
    return *reinterpret_cast<unsigned short*>(&h);
}
__device__ __forceinline__ float b2f(unsigned short u){
    __hip_bfloat16 h;
    *reinterpret_cast<unsigned short*>(&h) = u;
    return __bfloat162float(h);
}
__device__ __forceinline__ float b2f_lo(unsigned u){
    return __builtin_bit_cast(float, u << 16);
}
__device__ __forceinline__ float b2f_hi(unsigned u){
    return __builtin_bit_cast(float, u & 0xFFFF0000u);
}
__device__ __forceinline__ float gelu_f(float v){
    float u = 0.7978845608f*(v + 0.044715f*v*v*v);
    float e = __expf(2.f*u);
    float th = 1.f - 2.f*__builtin_amdgcn_rcpf(e + 1.f);
    return 0.5f*v*(1.f + th);
}
__device__ __forceinline__ void gload16(const unsigned short* g, unsigned short* l){
    __builtin_amdgcn_global_load_lds(
        (const __attribute__((address_space(1))) void*)g,
        (__attribute__((address_space(3))) void*)l, 16, 0, 0);
}
__device__ __forceinline__ void gload16f(const float* g, float* l){
    __builtin_amdgcn_global_load_lds(
        (const __attribute__((address_space(1))) void*)g,
        (__attribute__((address_space(3))) void*)l, 16, 0, 0);
}
template<int CTRL>
__device__ __forceinline__ float dppf(float x){
    int r = __builtin_amdgcn_mov_dpp(__builtin_bit_cast(int, x), CTRL, 0xf, 0xf, false);
    return __builtin_bit_cast(float, r);
}
template<int CTRL>
__device__ __forceinline__ int dppi(int x){
    return __builtin_amdgcn_mov_dpp(x, CTRL, 0xf, 0xf, false);
}

// ---------------- transpose + cast: W (KxN f32) -> Wt (NxK bf16) ----------
__global__ __launch_bounds__(256) void transpose_cast(
    const float* __restrict__ W, unsigned short* __restrict__ Wt, int K, int N)
{
    __shared__ float t[64*65];
    int n0 = blockIdx.x*64, k0 = blockIdx.y*64;
    int c = threadIdx.x & 63, r0 = threadIdx.x >> 6;
    #pragma unroll
    for (int rr = 0; rr < 64; rr += 4)
        t[(rr+r0)*65 + c] = W[(size_t)(k0+rr+r0)*N + n0 + c];
    __syncthreads();
    #pragma unroll
    for (int rr = 0; rr < 64; rr += 4)
        Wt[(size_t)(n0+rr+r0)*K + k0 + c] = f2b(t[c*65 + rr + r0]);
}

// ---------------- concat 3 bias vectors --------------------------------
__global__ __launch_bounds__(256) void concat_bias(
    const float* __restrict__ b0, const float* __restrict__ b1,
    const float* __restrict__ b2, float* __restrict__ o)
{
    int t = blockIdx.x*256 + threadIdx.x;
    float v = (t < 1024) ? b0[t] : (t < 2048 ? b1[t-1024] : b2[t-2048]);
    o[t] = v;
}

// ---------------- layernorm row=1024, f32 in -> bf16 out ------------------
__global__ __launch_bounds__(256) void layernorm_bf16(
    const float* __restrict__ x, const float* __restrict__ g,
    const float* __restrict__ b, unsigned short* __restrict__ out)
{
    int row = blockIdx.x;
    const float4* xr = (const float4*)(x + (size_t)row*DMODEL);
    int tid = threadIdx.x;
    float4 xv = xr[tid];
    float s  = xv.x + xv.y + xv.z + xv.w;
    float ss = xv.x*xv.x + xv.y*xv.y + xv.z*xv.z + xv.w*xv.w;
    #pragma unroll
    for (int d = 32; d > 0; d >>= 1){ s += __shfl_xor(s,d); ss += __shfl_xor(ss,d); }
    __shared__ float sm[8];
    int wv = tid>>6, ln = tid&63;
    if (ln == 0){ sm[wv] = s; sm[4+wv] = ss; }
    __syncthreads();
    s  = sm[0]+sm[1]+sm[2]+sm[3];
    ss = sm[4]+sm[5]+sm[6]+sm[7];
    float mean = s*(1.f/DMODEL);
    float var  = ss*(1.f/DMODEL) - mean*mean;
    float rstd = rsqrtf(var + 1e-5f);
    float4 gv = ((const float4*)g)[tid];
    float4 bv = ((const float4*)b)[tid];
    ushort4 o;
    o.x = f2b((xv.x-mean)*rstd*gv.x + bv.x);
    o.y = f2b((xv.y-mean)*rstd*gv.y + bv.y);
    o.z = f2b((xv.z-mean)*rstd*gv.z + bv.z);
    o.w = f2b((xv.w-mean)*rstd*gv.w + bv.w);
    ((ushort4*)(out + (size_t)row*DMODEL))[tid] = o;
}

// ---------------- GEMM: C[M,N] = act(A[M,K] @ Bt[N,K]^T + bias) (+res) ----
// 128x128 tile, 4 waves, each 64x64. BK=64. global_load_lds staging (m97).
template<int OUT_BF16, int HAS_RES, int ACT>
__global__ __launch_bounds__(256,2) void gemm_bt(
    const unsigned short* __restrict__ A, const unsigned short* __restrict__ Bt,
    const float* __restrict__ bias, const float* __restrict__ res,
    void* __restrict__ outp, int Ndim, int Kdim)
{
    __shared__ unsigned short As[128*64];   // unpadded: required by global_load_lds
    __shared__ unsigned short Bs[128*64];
    int tid = threadIdx.x;
    int lane = tid & 63, wv = tid >> 6;
    int l15 = lane & 15, quad = lane >> 4;
    int m0 = blockIdx.y*128, n0 = blockIdx.x*128;
    int mo = (wv>>1)*64, no = (wv&1)*64;
    int rsub = (lane >> 3);          // 0..7
    int cc8  = (lane & 7)*8;         // element col within 64
    f32x4 zz = {0.f,0.f,0.f,0.f};
    f32x4 acc[4][4];
    #pragma unroll
    for (int i=0;i<4;++i)
      #pragma unroll
      for (int j=0;j<4;++j) acc[i][j] = zz;

    for (int k0 = 0; k0 < Kdim; k0 += 64){
        const unsigned short* Ab = A  + (size_t)(m0 + wv*32 + rsub)*Kdim + k0 + cc8;
        const unsigned short* Bb = Bt + (size_t)(n0 + wv*32 + rsub)*Kdim + k0 + cc8;
        #pragma unroll
        for (int i=0;i<4;++i){
            gload16(Ab + (size_t)(i*8)*Kdim, &As[(wv*32 + i*8)*64]);
            gload16(Bb + (size_t)(i*8)*Kdim, &Bs[(wv*32 + i*8)*64]);
        }
        __syncthreads();
        #pragma unroll
        for (int kc=0;kc<2;++kc){
            bf16x8 af[4], bfr[4];
            #pragma unroll
            for (int t=0;t<4;++t){
                af[t]  = *(const bf16x8*)(&As[(mo + t*16 + l15)*64 + kc*32 + quad*8]);
                bfr[t] = *(const bf16x8*)(&Bs[(no + t*16 + l15)*64 + kc*32 + quad*8]);
            }
            #pragma unroll
            for (int mt=0;mt<4;++mt)
              #pragma unroll
              for (int nt=0;nt<4;++nt)
                acc[mt][nt] = __builtin_amdgcn_mfma_f32_16x16x32_bf16(af[mt], bfr[nt], acc[mt][nt], 0,0,0);
        }
        __syncthreads();
    }
    #pragma unroll
    for (int mt=0;mt<4;++mt){
      #pragma unroll
      for (int nt=0;nt<4;++nt){
        int gn = n0 + no + nt*16 + l15;
        float bval = bias[gn];
        #pragma unroll
        for (int r=0;r<4;++r){
            int gm = m0 + mo + mt*16 + quad*4 + r;
            size_t off = (size_t)gm*Ndim + gn;
            float v = acc[mt][nt][r] + bval;
            if constexpr (HAS_RES) v += res[off];
            if constexpr (ACT == 1) v = gelu_f(v);
            if constexpr (OUT_BF16) ((unsigned short*)outp)[off] = f2b(v);
            else                    ((float*)outp)[off] = v;
        }
      }
    }
}

// ---------------- flash attention, causal, 16 heads of 64 ------------------
// q/k/v live in the fused qkv buffer with row stride QKVLD.
__global__ __launch_bounds__(256,2) void attn_flash(
    const unsigned short* __restrict__ qkv, unsigned short* __restrict__ attn)
{
    __shared__ unsigned short Qs[64*72];
    __shared__ unsigned short Ks[64*72];
    __shared__ unsigned short Vt[64*72];
    __shared__ unsigned short Ps[64*72];
    int bh = blockIdx.y;
    int qt = (int)gridDim.x - 1 - (int)blockIdx.x;
    int q0 = qt*64;
    int tid = threadIdx.x, wv = tid>>6, lane = tid&63;
    int l15 = lane&15, quad = lane>>4;
    const size_t basei = (size_t)(bh>>4)*SEQ*QKVLD + (size_t)(bh&15)*64;
    const unsigned short* q = qkv + basei;
    const unsigned short* k = qkv + basei + DMODEL;
    const unsigned short* v = qkv + basei + 2*DMODEL;
    const size_t baseo = (size_t)(bh>>4)*SEQ*DMODEL + (size_t)(bh&15)*64;

    #pragma unroll
    for (int i=0;i<2;++i){
        int cch = tid + i*256; int r = cch>>3, cc = cch&7;
        *(uint4*)(&Qs[r*72 + cc*8]) = *(const uint4*)(q + (size_t)(q0+r)*QKVLD + cc*8);
    }
    __syncthreads();
    bf16x8 aq0 = *(const bf16x8*)(&Qs[(wv*16 + l15)*72 + quad*8]);
    bf16x8 aq1 = *(const bf16x8*)(&Qs[(wv*16 + l15)*72 + 32 + quad*8]);

    float m_i[4], l_i[4];
    f32x4 zz = {0.f,0.f,0.f,0.f};
    f32x4 o[4];
    #pragma unroll
    for (int r=0;r<4;++r){ m_i[r] = -__builtin_inff(); l_i[r] = 0.f; }
    #pragma unroll
    for (int d=0;d<4;++d) o[d] = zz;

    for (int kt = 0; kt <= qt; ++kt){
        int t0 = kt*64;
        #pragma unroll
        for (int i=0;i<2;++i){
            int cch = tid + i*256; int r = cch>>3, cc = cch&7;
            *(uint4*)(&Ks[r*72 + cc*8]) = *(const uint4*)(k + (size_t)(t0+r)*QKVLD + cc*8);
            uint4 vv = *(const uint4*)(v + (size_t)(t0+r)*QKVLD + cc*8);
            const unsigned short* pv = (const unsigned short*)&vv;
            #pragma unroll
            for (int j=0;j<8;++j) Vt[(cc*8+j)*72 + r] = pv[j];
        }
        __syncthreads();

        f32x4 sc[4];
        #pragma unroll
        for (int st=0;st<4;++st){
            bf16x8 b0 = *(const bf16x8*)(&Ks[(st*16+l15)*72 + quad*8]);
            bf16x8 b1 = *(const bf16x8*)(&Ks[(st*16+l15)*72 + 32 + quad*8]);
            sc[st] = __builtin_amdgcn_mfma_f32_16x16x32_bf16(aq0, b0, zz, 0,0,0);
            sc[st] = __builtin_amdgcn_mfma_f32_16x16x32_bf16(aq1, b1, sc[st], 0,0,0);
        }
        bool diag = (kt == qt);
        float sval[4][4];
        float mrow[4];
        #pragma unroll
        for (int r=0;r<4;++r) mrow[r] = -__builtin_inff();
        #pragma unroll
        for (int st=0;st<4;++st)
          #pragma unroll
          for (int r=0;r<4;++r){
            float svv = sc[st][r]*0.125f;
            if (diag && (st*16 + l15 > wv*16 + quad*4 + r)) svv = -__builtin_inff();
            sval[st][r] = svv;
            mrow[r] = fmaxf(mrow[r], svv);
          }
        #pragma unroll
        for (int d=1; d<16; d<<=1)
          #pragma unroll
          for (int r=0;r<4;++r) mrow[r] = fmaxf(mrow[r], __shfl_xor(mrow[r], d));
        float alpha[4], rsum[4];
        #pragma unroll
        for (int r=0;r<4;++r){
            float mn = fmaxf(m_i[r], mrow[r]);
            alpha[r] = __expf(m_i[r] - mn);
            m_i[r] = mn;
        }
        #pragma unroll
        for (int st=0;st<4;++st)
          #pragma unroll
          for (int r=0;r<4;++r) sval[st][r] = __expf(sval[st][r] - m_i[r]);
        #pragma unroll
        for (int r=0;r<4;++r) rsum[r] = sval[0][r]+sval[1][r]+sval[2][r]+sval[3][r];
        #pragma unroll
        for (int d=1; d<16; d<<=1)
          #pragma unroll
          for (int r=0;r<4;++r) rsum[r] += __shfl_xor(rsum[r], d);
        #pragma unroll
        for (int r=0;r<4;++r) l_i[r] = l_i[r]*alpha[r] + rsum[r];
        #pragma unroll
        for (int st=0;st<4;++st)
          #pragma unroll
          for (int r=0;r<4;++r)
            Ps[(wv*16 + quad*4 + r)*72 + st*16 + l15] = f2b(sval[st][r]);
        #pragma unroll
        for (int d=0;d<4;++d)
          #pragma unroll
          for (int r=0;r<4;++r) o[d][r] = o[d][r]*alpha[r];
        __syncthreads();
        bf16x8 ap0 = *(const bf16x8*)(&Ps[(wv*16 + l15)*72 + quad*8]);
        bf16x8 ap1 = *(const bf16x8*)(&Ps[(wv*16 + l15)*72 + 32 + quad*8]);
        #pragma unroll
        for (int dtile=0;dtile<4;++dtile){
            bf16x8 b0 = *(const bf16x8*)(&Vt[(dtile*16+l15)*72 + quad*8]);
            bf16x8 b1 = *(const bf16x8*)(&Vt[(dtile*16+l15)*72 + 32 + quad*8]);
            o[dtile] = __builtin_amdgcn_mfma_f32_16x16x32_bf16(ap0, b0, o[dtile], 0,0,0);
            o[dtile] = __builtin_amdgcn_mfma_f32_16x16x32_bf16(ap1, b1, o[dtile], 0,0,0);
        }
        __syncthreads();
    }
    #pragma unroll
    for (int r=0;r<4;++r){
        float inv = 1.f/l_i[r];
        int gm = q0 + wv*16 + quad*4 + r;
        #pragma unroll
        for (int dtile=0;dtile<4;++dtile)
            attn[baseo + (size_t)gm*DMODEL + dtile*16 + l15] = f2b(o[dtile][r]*inv);
    }
}

// ---------------- depthwise causal conv(4) + bias + silu -------------------
__global__ __launch_bounds__(256) void conv_silu(
    const unsigned short* __restrict__ xr, const float* __restrict__ cw,
    const float* __restrict__ cb, unsigned short* __restrict__ xm2)
{
    int idx = blockIdx.x*256 + threadIdx.x;
    int r  = idx >> 10;
    int c2 = (idx & 1023)*2;
    int s  = r & (SEQ-1);
    float4 w0 = *(const float4*)(cw + c2*4);
    float4 w1 = *(const float4*)(cw + (c2+1)*4);
    float w0a[4] = {w0.x,w0.y,w0.z,w0.w};
    float w1a[4] = {w1.x,w1.y,w1.z,w1.w};
    float a0 = cb[c2], a1 = cb[c2+1];
    const unsigned short* xrow = xr + (size_t)r*DFF + c2;
    #pragma unroll
    for (int j=0;j<4;++j){
        int sp = s - 3 + j;
        if (sp >= 0){
            int off = (j-3)*DFF;
            unsigned int u = *(const unsigned int*)(xrow + off);
            a0 += w0a[j]*b2f(u & 0xffff);
            a1 += w1a[j]*b2f(u >> 16);
        }
    }
    float s0 = a0 * __builtin_amdgcn_rcpf(1.f + __expf(-a0));
    float s1 = a1 * __builtin_amdgcn_rcpf(1.f + __expf(-a1));
    unsigned int op = (unsigned int)f2b(s0) | ((unsigned int)f2b(s1) << 16);
    *(unsigned int*)(xm2 + (size_t)r*DINNER + c2) = op;
}

// ---------------- xdbl = xm2 @ xp_w + xp_b, written as {b,c} pairs ---------
__global__ __launch_bounds__(256) void xp_gemm(
    const unsigned short* __restrict__ xm2, const float* __restrict__ w,
    const float* __restrict__ bias, float* __restrict__ xdbl)
{
    int tid = threadIdx.x;
    int lr = tid >> 5, n = tid & 31;
    int row = blockIdx.x*8 + lr;
    const unsigned short* ar = xm2 + (size_t)row*DINNER;
    float acc = bias[n];
    #pragma unroll 4
    for (int k2 = 0; k2 < DINNER; k2 += 2){
        unsigned int u = *(const unsigned int*)(ar + k2);
        acc += b2f(u & 0xffff)*w[k2*32 + n] + b2f(u >> 16)*w[(k2+1)*32 + n];
    }
    int nc = (n < 16) ? 2*n : 2*(n-16)+1;   // interleave: {b_i,c_i} adjacent
    xdbl[(size_t)row*32 + nc] = acc;
}

// ---------------- sequential scan: packed-bf16 register weights ------------
// h_{t+1}[i] = tanh(sum_j exp(dtp*A[i][j]) h_t[j]) + b_t[i]*h_t[i] + c_t[i]
// Weights pre-scaled by 2.0: x = sum (2W) h, tanh = 1 - 2/(e^x + 1).
__device__ __forceinline__ float scan_step_pk(float h, const unsigned (&Wp)[8],
                                              float bv, float cv)
{
    float r1  = dppf<0x121>(h);
    float r2  = dppf<0x122>(h);
    float r3  = dppf<0x123>(h);
    float r4  = dppf<0x124>(h);
    float r5  = dppf<0x125>(h);
    float r6  = dppf<0x126>(h);
    float r7  = dppf<0x127>(h);
    float r8  = dppf<0x128>(h);
    float r9  = dppf<0x129>(h);
    float r10 = dppf<0x12a>(h);
    float r11 = dppf<0x12b>(h);
    float r12 = dppf<0x12c>(h);
    float r13 = dppf<0x12d>(h);
    float r14 = dppf<0x12e>(h);
    float r15 = dppf<0x12f>(h);
    float a0 = b2f_lo(Wp[0])*h;
    a0 = fmaf(b2f_hi(Wp[0]), r1, a0);
    a0 = fmaf(b2f_lo(Wp[1]), r2, a0);
    a0 = fmaf(b2f_hi(Wp[1]), r3, a0);
    float a1 = b2f_lo(Wp[2])*r4;
    a1 = fmaf(b2f_hi(Wp[2]), r5, a1);
    a1 = fmaf(b2f_lo(Wp[3]), r6, a1);
    a1 = fmaf(b2f_hi(Wp[3]), r7, a1);
    float a2 = b2f_lo(Wp[4])*r8;
    a2 = fmaf(b2f_hi(Wp[4]), r9, a2);
    a2 = fmaf(b2f_lo(Wp[5]), r10, a2);
    a2 = fmaf(b2f_hi(Wp[5]), r11, a2);
    float a3 = b2f_lo(Wp[6])*r12;
    a3 = fmaf(b2f_hi(Wp[6]), r13, a3);
    a3 = fmaf(b2f_lo(Wp[7]), r14, a3);
    a3 = fmaf(b2f_hi(Wp[7]), r15, a3);
    float x = (a0+a1)+(a2+a3);              // = 2*s (weights pre-scaled)
    float e2 = __expf(x);
    float th = 1.f - 2.f*__builtin_amdgcn_rcpf(e2 + 1.f);
    return th + fmaf(bv, h, cv);
}

__global__ __launch_bounds__(128,1) void scan_k(
    const float* __restrict__ xdbl, const float* __restrict__ dt,
    const float* __restrict__ A, float* __restrict__ hsT)
{
    __shared__ float bc[2][2][64*32];   // [wave][buf][step*32 + 2*i{b,c}]
    int tid = threadIdx.x;
    int wv = tid >> 6, lane = tid & 63;
    int i = lane & 15;
    int b = wv;

    // probe: identical DPP fan applied to lane index -> source-lane order
    int c[16];
    c[0]  = i;
    c[1]  = dppi<0x121>(i);
    c[2]  = dppi<0x122>(i);
    c[3]  = dppi<0x123>(i);
    c[4]  = dppi<0x124>(i);
    c[5]  = dppi<0x125>(i);
    c[6]  = dppi<0x126>(i);
    c[7]  = dppi<0x127>(i);
    c[8]  = dppi<0x128>(i);
    c[9]  = dppi<0x129>(i);
    c[10] = dppi<0x12a>(i);
    c[11] = dppi<0x12b>(i);
    c[12] = dppi<0x12c>(i);
    c[13] = dppi<0x12d>(i);
    c[14] = dppi<0x12e>(i);
    c[15] = dppi<0x12f>(i);

    // packed-bf16 weight table: 16 phases x 8 uints = 128 VGPRs
    unsigned Wpk[16][8];
    #pragma unroll
    for (int p=0;p<16;++p){
        float dtp = __expf(dt[p]);
        #pragma unroll
        for (int jj=0;jj<8;++jj){
            float w0 = 2.f*__expf(dtp * A[i*16 + c[2*jj]]);
            float w1 = 2.f*__expf(dtp * A[i*16 + c[2*jj+1]]);
            Wpk[p][jj] = (unsigned)f2b(w0) | ((unsigned)f2b(w1) << 16);
        }
    }

    // stage chunk 0 via global_load_lds (8KB per wave)
    {
        const float* src = xdbl + (size_t)(b*SEQ)*32 + lane*4;
        #pragma unroll
        for (int k=0;k<8;++k)
            gload16f(src + k*256, &bc[wv][0][k*256]);
    }
    __builtin_amdgcn_s_waitcnt(0x0F70);   // vmcnt(0)

    float hn = 0.f;
    float h0s=0.f, h1s=0.f, h2s=0.f;
    for (int chunk = 0; chunk < 32; ++chunk){
        if (chunk < 31){   // stage next chunk into the other buffer
            const float* nsrc = xdbl + (size_t)(b*SEQ + (chunk+1)*64)*32 + lane*4;
            float* nb = &bc[wv][(chunk+1)&1][0];
            #pragma unroll
            for (int k=0;k<8;++k)
                gload16f(nsrc + k*256, nb + k*256);
        }
        const float* cur = &bc[wv][chunk&1][0];
        float* hp = hsT + (size_t)(b*16 + i)*SEQ + chunk*64;
        float2 bc0 = *(const float2*)(cur + 2*i);          // step 0
        float2 bc1 = *(const float2*)(cur + 32 + 2*i);     // step 1
        #pragma unroll
        for (int st=0; st<64; ++st){
            float bv = bc0.x, cv = bc0.y;
            bc0 = bc1;
            if (st < 62)
                bc1 = *(const float2*)(cur + (st+2)*32 + 2*i);  // imm offset
            hn = scan_step_pk(hn, Wpk[st & 15], bv, cv);
            if ((st&3)==0)      h0s = hn;
            else if ((st&3)==1) h1s = hn;
            else if ((st&3)==2) h2s = hn;
            else if (lane < 16){
                float4 o4 = {h0s, h1s, h2s, hn};
                *(float4*)(hp + (st-3)) = o4;               // 1 store / 4 steps
            }
        }
        __builtin_amdgcn_s_waitcnt(0x0F70);   // vmcnt(0): next buffer staged
    }
}

// ---------------- y = repeat(hsT,128) + res (bf16) -------------------------
__global__ __launch_bounds__(256) void y_assemble(
    const float* __restrict__ hsT, const unsigned short* __restrict__ xr,
    unsigned short* __restrict__ y)
{
    int idx = blockIdx.x*256 + threadIdx.x;
    int r = idx >> 10;
    int c2 = (idx & 1023)*2;
    int bb = r >> 11, s = r & (SEQ-1);
    unsigned int u = *(const unsigned int*)(xr + (size_t)r*DFF + DINNER + c2);
    float h0 = hsT[(size_t)(bb*16 + (c2 >> 7))*SEQ + s];
    float y0 = h0 + b2f(u & 0xffff);
    float y1 = h0 + b2f(u >> 16);
    *(unsigned int*)(y + (size_t)r*DINNER + c2) =
        (unsigned int)f2b(y0) | ((unsigned int)f2b(y1) << 16);
}

// ---------------------------------------------------------------------------
extern "C" void kernel_launch(void* const* d_in, const int* in_sizes, int n_in,
                              void* d_out, int out_size, void* d_ws, size_t ws_size,
                              hipStream_t stream)
{
    (void)in_sizes; (void)n_in; (void)out_size; (void)ws_size;
    const float* x     = (const float*)d_in[0];
    const float* ln1_g = (const float*)d_in[1];
    const float* ln1_b = (const float*)d_in[2];
    const float* Wq    = (const float*)d_in[3];
    const float* bq    = (const float*)d_in[4];
    const float* Wk    = (const float*)d_in[5];
    const float* bk    = (const float*)d_in[6];
    const float* Wv    = (const float*)d_in[7];
    const float* bv    = (const float*)d_in[8];
    const float* Wo    = (const float*)d_in[9];
    const float* bo    = (const float*)d_in[10];
    const float* ln2_g = (const float*)d_in[11];
    const float* ln2_b = (const float*)d_in[12];
    const float* in_w  = (const float*)d_in[13];
    const float* in_b  = (const float*)d_in[14];
    const float* conv_w= (const float*)d_in[15];
    const float* conv_b= (const float*)d_in[16];
    const float* xp_w  = (const float*)d_in[17];
    const float* xp_b  = (const float*)d_in[18];
    const float* dt    = (const float*)d_in[19];
    const float* A     = (const float*)d_in[20];
    const float* out_w = (const float*)d_in[22];
    const float* out_b = (const float*)d_in[23];
    const float* ln3_g = (const float*)d_in[24];
    const float* ln3_b = (const float*)d_in[25];
    const float* fc1_w = (const float*)d_in[26];
    const float* fc1_b = (const float*)d_in[27];
    const float* fc2_w = (const float*)d_in[28];
    const float* fc2_b = (const float*)d_in[29];

    char* ws = (char*)d_ws;
    const size_t MB = 1ull << 20;
    unsigned short* qkvT = (unsigned short*)(ws + 0*MB);   // WqT|WkT|WvT, 6MB
    unsigned short* WoT  = (unsigned short*)(ws + 6*MB);
    unsigned short* inT  = (unsigned short*)(ws + 8*MB);
    unsigned short* outT = (unsigned short*)(ws + 16*MB);
    unsigned short* f1T  = (unsigned short*)(ws + 20*MB);
    unsigned short* f2T  = (unsigned short*)(ws + 28*MB);
    unsigned short* hbf  = (unsigned short*)(ws + 36*MB);
    float*          x2   = (float*)(ws + 44*MB);
    float*          x3   = (float*)(ws + 60*MB);
    unsigned short* qkv  = (unsigned short*)(ws + 76*MB);  // 24MB fused QKV
    unsigned short* attnb= (unsigned short*)(ws + 100*MB);
    unsigned short* xr   = (unsigned short*)(ws + 76*MB);  // reuse after attn
    unsigned short* ffn  = (unsigned short*)(ws + 76*MB);  // reuse after y
    unsigned short* xm2  = (unsigned short*)(ws + 108*MB);
    unsigned short* yb   = (unsigned short*)(ws + 108*MB); // reuse after xp
    float*          xdbl = (float*)(ws + 124*MB);
    float*          hsb  = (float*)(ws + 124*MB + 512*1024);
    float*          bqkv = (float*)(ws + 125*MB);

    dim3 blk(256);
    transpose_cast<<<dim3(16,16), blk, 0, stream>>>(Wq, qkvT,              1024, 1024);
    transpose_cast<<<dim3(16,16), blk, 0, stream>>>(Wk, qkvT + 1024*1024,  1024, 1024);
    transpose_cast<<<dim3(16,16), blk, 0, stream>>>(Wv, qkvT + 2*1024*1024,1024, 1024);
    transpose_cast<<<dim3(16,16), blk, 0, stream>>>(Wo, WoT, 1024, 1024);
    transpose_cast<<<dim3(64,16), blk, 0, stream>>>(in_w, inT, 1024, 4096);
    transpose_cast<<<dim3(16,32), blk, 0, stream>>>(out_w, outT, 2048, 1024);
    transpose_cast<<<dim3(64,16), blk, 0, stream>>>(fc1_w, f1T, 1024, 4096);
    transpose_cast<<<dim3(16,64), blk, 0, stream>>>(fc2_w, f2T, 4096, 1024);
    concat_bias<<<12, blk, 0, stream>>>(bq, bk, bv, bqkv);

    layernorm_bf16<<<MROWS, blk, 0, stream>>>(x, ln1_g, ln1_b, hbf);
    gemm_bt<1,0,0><<<dim3(24,32), blk, 0, stream>>>(hbf, qkvT, bqkv, nullptr, qkv, QKVLD, 1024);
    attn_flash<<<dim3(32,32), blk, 0, stream>>>(qkv, attnb);
    gemm_bt<0,1,0><<<dim3(8,32),  blk, 0, stream>>>(attnb, WoT, bo, x, x2, 1024, 1024);
    layernorm_bf16<<<MROWS, blk, 0, stream>>>(x2, ln2_g, ln2_b, hbf);
    gemm_bt<1,0,0><<<dim3(32,32), blk, 0, stream>>>(hbf, inT, in_b, nullptr, xr, 4096, 1024);
    conv_silu<<<16384, blk, 0, stream>>>(xr, conv_w, conv_b, xm2);
    xp_gemm<<<512, blk, 0, stream>>>(xm2, xp_w, xp_b, xdbl);
    scan_k<<<1, dim3(128), 0, stream>>>(xdbl, dt, A, hsb);
    y_assemble<<<16384, blk, 0, stream>>>(hsb, xr, yb);
    gemm_bt<0,1,0><<<dim3(8,32),  blk, 0, stream>>>(yb, outT, out_b, x2, x3, 1024, 2048);
    layernorm_bf16<<<MROWS, blk, 0, stream>>>(x3, ln3_g, ln3_b, hbf);
    gemm_bt<1,0,1><<<dim3(32,32), blk, 0, stream>>>(hbf, f1T, fc1_b, nullptr, ffn, 4096, 1024);
    gemm_bt<0,1,0><<<dim3(8,32),  blk, 0, stream>>>(ffn, f2T, fc2_b, x3, (float*)d_out, 1024, 4096);
}

// Round 7
// 993.932 us; speedup vs baseline: 1.1688x; 1.0221x over previous
//
#include <hip/hip_runtime.h>
#include <hip/hip_bf16.h>

// ---------------------------------------------------------------------------
// R7 changes vs R6:
//  * gemm_bt templated on BN. N=1024 GEMMs (Wo, out_w, fc2) now use 128x64
//    tiles -> 512 blocks = 2 blocks/CU (was 256 = 1/CU, fully exposing every
//    K-loop barrier drain; m97's TF numbers require >=2 co-resident blocks).
//    N>=3072 GEMMs keep 128x128.
//  * scan_k unchanged (210us, 72% issue-bound on its math core).
// ---------------------------------------------------------------------------

#define SEQ     2048
#define BATCH   2
#define MROWS   4096      // BATCH*SEQ
#define DMODEL  1024
#define DINNER  2048
#define DFF     4096
#define QKVLD   3072

typedef __attribute__((ext_vector_type(8))) short bf16x8;
typedef __attribute__((ext_vector_type(4))) float f32x4;

__device__ __forceinline__ unsigned short f2b(float x){
    __hip_bfloat16 h = __float2bfloat16(x);
    return *reinterpret_cast<unsigned short*>(&h);
}
__device__ __forceinline__ float b2f(unsigned short u){
    __hip_bfloat16 h;
    *reinterpret_cast<unsigned short*>(&h) = u;
    return __bfloat162float(h);
}
__device__ __forceinline__ float b2f_lo(unsigned u){
    return __builtin_bit_cast(float, u << 16);
}
__device__ __forceinline__ float b2f_hi(unsigned u){
    return __builtin_bit_cast(float, u & 0xFFFF0000u);
}
__device__ __forceinline__ float gelu_f(float v){
    float u = 0.7978845608f*(v + 0.044715f*v*v*v);
    float e = __expf(2.f*u);
    float th = 1.f - 2.f*__builtin_amdgcn_rcpf(e + 1.f);
    return 0.5f*v*(1.f + th);
}
__device__ __forceinline__ void gload16(const unsigned short* g, unsigned short* l){
    __builtin_amdgcn_global_load_lds(
        (const __attribute__((address_space(1))) void*)g,
        (__attribute__((address_space(3))) void*)l, 16, 0, 0);
}
__device__ __forceinline__ void gload16f(const float* g, float* l){
    __builtin_amdgcn_global_load_lds(
        (const __attribute__((address_space(1))) void*)g,
        (__attribute__((address_space(3))) void*)l, 16, 0, 0);
}
template<int CTRL>
__device__ __forceinline__ float dppf(float x){
    int r = __builtin_amdgcn_mov_dpp(__builtin_bit_cast(int, x), CTRL, 0xf, 0xf, false);
    return __builtin_bit_cast(float, r);
}
template<int CTRL>
__device__ __forceinline__ int dppi(int x){
    return __builtin_amdgcn_mov_dpp(x, CTRL, 0xf, 0xf, false);
}

// ---------------- transpose + cast: W (KxN f32) -> Wt (NxK bf16) ----------
__global__ __launch_bounds__(256) void transpose_cast(
    const float* __restrict__ W, unsigned short* __restrict__ Wt, int K, int N)
{
    __shared__ float t[64*65];
    int n0 = blockIdx.x*64, k0 = blockIdx.y*64;
    int c = threadIdx.x & 63, r0 = threadIdx.x >> 6;
    #pragma unroll
    for (int rr = 0; rr < 64; rr += 4)
        t[(rr+r0)*65 + c] = W[(size_t)(k0+rr+r0)*N + n0 + c];
    __syncthreads();
    #pragma unroll
    for (int rr = 0; rr < 64; rr += 4)
        Wt[(size_t)(n0+rr+r0)*K + k0 + c] = f2b(t[c*65 + rr + r0]);
}

// ---------------- concat 3 bias vectors --------------------------------
__global__ __launch_bounds__(256) void concat_bias(
    const float* __restrict__ b0, const float* __restrict__ b1,
    const float* __restrict__ b2, float* __restrict__ o)
{
    int t = blockIdx.x*256 + threadIdx.x;
    float v = (t < 1024) ? b0[t] : (t < 2048 ? b1[t-1024] : b2[t-2048]);
    o[t] = v;
}

// ---------------- layernorm row=1024, f32 in -> bf16 out ------------------
__global__ __launch_bounds__(256) void layernorm_bf16(
    const float* __restrict__ x, const float* __restrict__ g,
    const float* __restrict__ b, unsigned short* __restrict__ out)
{
    int row = blockIdx.x;
    const float4* xr = (const float4*)(x + (size_t)row*DMODEL);
    int tid = threadIdx.x;
    float4 xv = xr[tid];
    float s  = xv.x + xv.y + xv.z + xv.w;
    float ss = xv.x*xv.x + xv.y*xv.y + xv.z*xv.z + xv.w*xv.w;
    #pragma unroll
    for (int d = 32; d > 0; d >>= 1){ s += __shfl_xor(s,d); ss += __shfl_xor(ss,d); }
    __shared__ float sm[8];
    int wv = tid>>6, ln = tid&63;
    if (ln == 0){ sm[wv] = s; sm[4+wv] = ss; }
    __syncthreads();
    s  = sm[0]+sm[1]+sm[2]+sm[3];
    ss = sm[4]+sm[5]+sm[6]+sm[7];
    float mean = s*(1.f/DMODEL);
    float var  = ss*(1.f/DMODEL) - mean*mean;
    float rstd = rsqrtf(var + 1e-5f);
    float4 gv = ((const float4*)g)[tid];
    float4 bv = ((const float4*)b)[tid];
    ushort4 o;
    o.x = f2b((xv.x-mean)*rstd*gv.x + bv.x);
    o.y = f2b((xv.y-mean)*rstd*gv.y + bv.y);
    o.z = f2b((xv.z-mean)*rstd*gv.z + bv.z);
    o.w = f2b((xv.w-mean)*rstd*gv.w + bv.w);
    ((ushort4*)(out + (size_t)row*DMODEL))[tid] = o;
}

// ---------------- GEMM: C[M,N] = act(A[M,K] @ Bt[N,K]^T + bias) (+res) ----
// 128xBN tile, 4 waves (2x2), wave does 64x(BN/2). BK=64. global_load_lds.
template<int BN, int OUT_BF16, int HAS_RES, int ACT>
__global__ __launch_bounds__(256,2) void gemm_bt(
    const unsigned short* __restrict__ A, const unsigned short* __restrict__ Bt,
    const float* __restrict__ bias, const float* __restrict__ res,
    void* __restrict__ outp, int Ndim, int Kdim)
{
    constexpr int NT = BN/32;               // n-tiles per wave
    constexpr int BROWS = BN/32;            // B staging iters per wave (8 rows each)
    __shared__ unsigned short As[128*64];   // unpadded: required by global_load_lds
    __shared__ unsigned short Bs[BN*64];
    int tid = threadIdx.x;
    int lane = tid & 63, wv = tid >> 6;
    int l15 = lane & 15, quad = lane >> 4;
    int m0 = blockIdx.y*128, n0 = blockIdx.x*BN;
    int mo = (wv>>1)*64, no = (wv&1)*(BN/2);
    int rsub = (lane >> 3);          // 0..7
    int cc8  = (lane & 7)*8;         // element col within 64
    f32x4 zz = {0.f,0.f,0.f,0.f};
    f32x4 acc[4][NT];
    #pragma unroll
    for (int i=0;i<4;++i)
      #pragma unroll
      for (int j=0;j<NT;++j) acc[i][j] = zz;

    for (int k0 = 0; k0 < Kdim; k0 += 64){
        const unsigned short* Ab = A  + (size_t)(m0 + wv*32 + rsub)*Kdim + k0 + cc8;
        const unsigned short* Bb = Bt + (size_t)(n0 + wv*(BN/4) + rsub)*Kdim + k0 + cc8;
        #pragma unroll
        for (int i=0;i<4;++i)
            gload16(Ab + (size_t)(i*8)*Kdim, &As[(wv*32 + i*8)*64]);
        #pragma unroll
        for (int i=0;i<BROWS;++i)
            gload16(Bb + (size_t)(i*8)*Kdim, &Bs[(wv*(BN/4) + i*8)*64]);
        __syncthreads();
        #pragma unroll
        for (int kc=0;kc<2;++kc){
            bf16x8 af[4], bfr[NT];
            #pragma unroll
            for (int t=0;t<4;++t)
                af[t]  = *(const bf16x8*)(&As[(mo + t*16 + l15)*64 + kc*32 + quad*8]);
            #pragma unroll
            for (int t=0;t<NT;++t)
                bfr[t] = *(const bf16x8*)(&Bs[(no + t*16 + l15)*64 + kc*32 + quad*8]);
            #pragma unroll
            for (int mt=0;mt<4;++mt)
              #pragma unroll
              for (int nt=0;nt<NT;++nt)
                acc[mt][nt] = __builtin_amdgcn_mfma_f32_16x16x32_bf16(af[mt], bfr[nt], acc[mt][nt], 0,0,0);
        }
        __syncthreads();
    }
    #pragma unroll
    for (int mt=0;mt<4;++mt){
      #pragma unroll
      for (int nt=0;nt<NT;++nt){
        int gn = n0 + no + nt*16 + l15;
        float bval = bias[gn];
        #pragma unroll
        for (int r=0;r<4;++r){
            int gm = m0 + mo + mt*16 + quad*4 + r;
            size_t off = (size_t)gm*Ndim + gn;
            float v = acc[mt][nt][r] + bval;
            if constexpr (HAS_RES) v += res[off];
            if constexpr (ACT == 1) v = gelu_f(v);
            if constexpr (OUT_BF16) ((unsigned short*)outp)[off] = f2b(v);
            else                    ((float*)outp)[off] = v;
        }
      }
    }
}

// ---------------- flash attention, causal, 16 heads of 64 ------------------
// q/k/v live in the fused qkv buffer with row stride QKVLD.
__global__ __launch_bounds__(256,2) void attn_flash(
    const unsigned short* __restrict__ qkv, unsigned short* __restrict__ attn)
{
    __shared__ unsigned short Qs[64*72];
    __shared__ unsigned short Ks[64*72];
    __shared__ unsigned short Vt[64*72];
    __shared__ unsigned short Ps[64*72];
    int bh = blockIdx.y;
    int qt = (int)gridDim.x - 1 - (int)blockIdx.x;
    int q0 = qt*64;
    int tid = threadIdx.x, wv = tid>>6, lane = tid&63;
    int l15 = lane&15, quad = lane>>4;
    const size_t basei = (size_t)(bh>>4)*SEQ*QKVLD + (size_t)(bh&15)*64;
    const unsigned short* q = qkv + basei;
    const unsigned short* k = qkv + basei + DMODEL;
    const unsigned short* v = qkv + basei + 2*DMODEL;
    const size_t baseo = (size_t)(bh>>4)*SEQ*DMODEL + (size_t)(bh&15)*64;

    #pragma unroll
    for (int i=0;i<2;++i){
        int cch = tid + i*256; int r = cch>>3, cc = cch&7;
        *(uint4*)(&Qs[r*72 + cc*8]) = *(const uint4*)(q + (size_t)(q0+r)*QKVLD + cc*8);
    }
    __syncthreads();
    bf16x8 aq0 = *(const bf16x8*)(&Qs[(wv*16 + l15)*72 + quad*8]);
    bf16x8 aq1 = *(const bf16x8*)(&Qs[(wv*16 + l15)*72 + 32 + quad*8]);

    float m_i[4], l_i[4];
    f32x4 zz = {0.f,0.f,0.f,0.f};
    f32x4 o[4];
    #pragma unroll
    for (int r=0;r<4;++r){ m_i[r] = -__builtin_inff(); l_i[r] = 0.f; }
    #pragma unroll
    for (int d=0;d<4;++d) o[d] = zz;

    for (int kt = 0; kt <= qt; ++kt){
        int t0 = kt*64;
        #pragma unroll
        for (int i=0;i<2;++i){
            int cch = tid + i*256; int r = cch>>3, cc = cch&7;
            *(uint4*)(&Ks[r*72 + cc*8]) = *(const uint4*)(k + (size_t)(t0+r)*QKVLD + cc*8);
            uint4 vv = *(const uint4*)(v + (size_t)(t0+r)*QKVLD + cc*8);
            const unsigned short* pv = (const unsigned short*)&vv;
            #pragma unroll
            for (int j=0;j<8;++j) Vt[(cc*8+j)*72 + r] = pv[j];
        }
        __syncthreads();

        f32x4 sc[4];
        #pragma unroll
        for (int st=0;st<4;++st){
            bf16x8 b0 = *(const bf16x8*)(&Ks[(st*16+l15)*72 + quad*8]);
            bf16x8 b1 = *(const bf16x8*)(&Ks[(st*16+l15)*72 + 32 + quad*8]);
            sc[st] = __builtin_amdgcn_mfma_f32_16x16x32_bf16(aq0, b0, zz, 0,0,0);
            sc[st] = __builtin_amdgcn_mfma_f32_16x16x32_bf16(aq1, b1, sc[st], 0,0,0);
        }
        bool diag = (kt == qt);
        float sval[4][4];
        float mrow[4];
        #pragma unroll
        for (int r=0;r<4;++r) mrow[r] = -__builtin_inff();
        #pragma unroll
        for (int st=0;st<4;++st)
          #pragma unroll
          for (int r=0;r<4;++r){
            float svv = sc[st][r]*0.125f;
            if (diag && (st*16 + l15 > wv*16 + quad*4 + r)) svv = -__builtin_inff();
            sval[st][r] = svv;
            mrow[r] = fmaxf(mrow[r], svv);
          }
        #pragma unroll
        for (int d=1; d<16; d<<=1)
          #pragma unroll
          for (int r=0;r<4;++r) mrow[r] = fmaxf(mrow[r], __shfl_xor(mrow[r], d));
        float alpha[4], rsum[4];
        #pragma unroll
        for (int r=0;r<4;++r){
            float mn = fmaxf(m_i[r], mrow[r]);
            alpha[r] = __expf(m_i[r] - mn);
            m_i[r] = mn;
        }
        #pragma unroll
        for (int st=0;st<4;++st)
          #pragma unroll
          for (int r=0;r<4;++r) sval[st][r] = __expf(sval[st][r] - m_i[r]);
        #pragma unroll
        for (int r=0;r<4;++r) rsum[r] = sval[0][r]+sval[1][r]+sval[2][r]+sval[3][r];
        #pragma unroll
        for (int d=1; d<16; d<<=1)
          #pragma unroll
          for (int r=0;r<4;++r) rsum[r] += __shfl_xor(rsum[r], d);
        #pragma unroll
        for (int r=0;r<4;++r) l_i[r] = l_i[r]*alpha[r] + rsum[r];
        #pragma unroll
        for (int st=0;st<4;++st)
          #pragma unroll
          for (int r=0;r<4;++r)
            Ps[(wv*16 + quad*4 + r)*72 + st*16 + l15] = f2b(sval[st][r]);
        #pragma unroll
        for (int d=0;d<4;++d)
          #pragma unroll
          for (int r=0;r<4;++r) o[d][r] = o[d][r]*alpha[r];
        __syncthreads();
        bf16x8 ap0 = *(const bf16x8*)(&Ps[(wv*16 + l15)*72 + quad*8]);
        bf16x8 ap1 = *(const bf16x8*)(&Ps[(wv*16 + l15)*72 + 32 + quad*8]);
        #pragma unroll
        for (int dtile=0;dtile<4;++dtile){
            bf16x8 b0 = *(const bf16x8*)(&Vt[(dtile*16+l15)*72 + quad*8]);
            bf16x8 b1 = *(const bf16x8*)(&Vt[(dtile*16+l15)*72 + 32 + quad*8]);
            o[dtile] = __builtin_amdgcn_mfma_f32_16x16x32_bf16(ap0, b0, o[dtile], 0,0,0);
            o[dtile] = __builtin_amdgcn_mfma_f32_16x16x32_bf16(ap1, b1, o[dtile], 0,0,0);
        }
        __syncthreads();
    }
    #pragma unroll
    for (int r=0;r<4;++r){
        float inv = 1.f/l_i[r];
        int gm = q0 + wv*16 + quad*4 + r;
        #pragma unroll
        for (int dtile=0;dtile<4;++dtile)
            attn[baseo + (size_t)gm*DMODEL + dtile*16 + l15] = f2b(o[dtile][r]*inv);
    }
}

// ---------------- depthwise causal conv(4) + bias + silu -------------------
__global__ __launch_bounds__(256) void conv_silu(
    const unsigned short* __restrict__ xr, const float* __restrict__ cw,
    const float* __restrict__ cb, unsigned short* __restrict__ xm2)
{
    int idx = blockIdx.x*256 + threadIdx.x;
    int r  = idx >> 10;
    int c2 = (idx & 1023)*2;
    int s  = r & (SEQ-1);
    float4 w0 = *(const float4*)(cw + c2*4);
    float4 w1 = *(const float4*)(cw + (c2+1)*4);
    float w0a[4] = {w0.x,w0.y,w0.z,w0.w};
    float w1a[4] = {w1.x,w1.y,w1.z,w1.w};
    float a0 = cb[c2], a1 = cb[c2+1];
    const unsigned short* xrow = xr + (size_t)r*DFF + c2;
    #pragma unroll
    for (int j=0;j<4;++j){
        int sp = s - 3 + j;
        if (sp >= 0){
            int off = (j-3)*DFF;
            unsigned int u = *(const unsigned int*)(xrow + off);
            a0 += w0a[j]*b2f(u & 0xffff);
            a1 += w1a[j]*b2f(u >> 16);
        }
    }
    float s0 = a0 * __builtin_amdgcn_rcpf(1.f + __expf(-a0));
    float s1 = a1 * __builtin_amdgcn_rcpf(1.f + __expf(-a1));
    unsigned int op = (unsigned int)f2b(s0) | ((unsigned int)f2b(s1) << 16);
    *(unsigned int*)(xm2 + (size_t)r*DINNER + c2) = op;
}

// ---------------- xdbl = xm2 @ xp_w + xp_b, written as {b,c} pairs ---------
__global__ __launch_bounds__(256) void xp_gemm(
    const unsigned short* __restrict__ xm2, const float* __restrict__ w,
    const float* __restrict__ bias, float* __restrict__ xdbl)
{
    int tid = threadIdx.x;
    int lr = tid >> 5, n = tid & 31;
    int row = blockIdx.x*8 + lr;
    const unsigned short* ar = xm2 + (size_t)row*DINNER;
    float acc = bias[n];
    #pragma unroll 4
    for (int k2 = 0; k2 < DINNER; k2 += 2){
        unsigned int u = *(const unsigned int*)(ar + k2);
        acc += b2f(u & 0xffff)*w[k2*32 + n] + b2f(u >> 16)*w[(k2+1)*32 + n];
    }
    int nc = (n < 16) ? 2*n : 2*(n-16)+1;   // interleave: {b_i,c_i} adjacent
    xdbl[(size_t)row*32 + nc] = acc;
}

// ---------------- sequential scan: packed-bf16 register weights ------------
// h_{t+1}[i] = tanh(sum_j exp(dtp*A[i][j]) h_t[j]) + b_t[i]*h_t[i] + c_t[i]
// Weights pre-scaled by 2.0: x = sum (2W) h, tanh = 1 - 2/(e^x + 1).
__device__ __forceinline__ float scan_step_pk(float h, const unsigned (&Wp)[8],
                                              float bv, float cv)
{
    float r1  = dppf<0x121>(h);
    float r2  = dppf<0x122>(h);
    float r3  = dppf<0x123>(h);
    float r4  = dppf<0x124>(h);
    float r5  = dppf<0x125>(h);
    float r6  = dppf<0x126>(h);
    float r7  = dppf<0x127>(h);
    float r8  = dppf<0x128>(h);
    float r9  = dppf<0x129>(h);
    float r10 = dppf<0x12a>(h);
    float r11 = dppf<0x12b>(h);
    float r12 = dppf<0x12c>(h);
    float r13 = dppf<0x12d>(h);
    float r14 = dppf<0x12e>(h);
    float r15 = dppf<0x12f>(h);
    float a0 = b2f_lo(Wp[0])*h;
    a0 = fmaf(b2f_hi(Wp[0]), r1, a0);
    a0 = fmaf(b2f_lo(Wp[1]), r2, a0);
    a0 = fmaf(b2f_hi(Wp[1]), r3, a0);
    float a1 = b2f_lo(Wp[2])*r4;
    a1 = fmaf(b2f_hi(Wp[2]), r5, a1);
    a1 = fmaf(b2f_lo(Wp[3]), r6, a1);
    a1 = fmaf(b2f_hi(Wp[3]), r7, a1);
    float a2 = b2f_lo(Wp[4])*r8;
    a2 = fmaf(b2f_hi(Wp[4]), r9, a2);
    a2 = fmaf(b2f_lo(Wp[5]), r10, a2);
    a2 = fmaf(b2f_hi(Wp[5]), r11, a2);
    float a3 = b2f_lo(Wp[6])*r12;
    a3 = fmaf(b2f_hi(Wp[6]), r13, a3);
    a3 = fmaf(b2f_lo(Wp[7]), r14, a3);
    a3 = fmaf(b2f_hi(Wp[7]), r15, a3);
    float x = (a0+a1)+(a2+a3);              // = 2*s (weights pre-scaled)
    float e2 = __expf(x);
    float th = 1.f - 2.f*__builtin_amdgcn_rcpf(e2 + 1.f);
    return th + fmaf(bv, h, cv);
}

__global__ __launch_bounds__(128,1) void scan_k(
    const float* __restrict__ xdbl, const float* __restrict__ dt,
    const float* __restrict__ A, float* __restrict__ hsT)
{
    __shared__ float bc[2][2][64*32];   // [wave][buf][step*32 + 2*i{b,c}]
    int tid = threadIdx.x;
    int wv = tid >> 6, lane = tid & 63;
    int i = lane & 15;
    int b = wv;

    // probe: identical DPP fan applied to lane index -> source-lane order
    int c[16];
    c[0]  = i;
    c[1]  = dppi<0x121>(i);
    c[2]  = dppi<0x122>(i);
    c[3]  = dppi<0x123>(i);
    c[4]  = dppi<0x124>(i);
    c[5]  = dppi<0x125>(i);
    c[6]  = dppi<0x126>(i);
    c[7]  = dppi<0x127>(i);
    c[8]  = dppi<0x128>(i);
    c[9]  = dppi<0x129>(i);
    c[10] = dppi<0x12a>(i);
    c[11] = dppi<0x12b>(i);
    c[12] = dppi<0x12c>(i);
    c[13] = dppi<0x12d>(i);
    c[14] = dppi<0x12e>(i);
    c[15] = dppi<0x12f>(i);

    // packed-bf16 weight table: 16 phases x 8 uints = 128 VGPRs
    unsigned Wpk[16][8];
    #pragma unroll
    for (int p=0;p<16;++p){
        float dtp = __expf(dt[p]);
        #pragma unroll
        for (int jj=0;jj<8;++jj){
            float w0 = 2.f*__expf(dtp * A[i*16 + c[2*jj]]);
            float w1 = 2.f*__expf(dtp * A[i*16 + c[2*jj+1]]);
            Wpk[p][jj] = (unsigned)f2b(w0) | ((unsigned)f2b(w1) << 16);
        }
    }

    // stage chunk 0 via global_load_lds (8KB per wave)
    {
        const float* src = xdbl + (size_t)(b*SEQ)*32 + lane*4;
        #pragma unroll
        for (int k=0;k<8;++k)
            gload16f(src + k*256, &bc[wv][0][k*256]);
    }
    __builtin_amdgcn_s_waitcnt(0x0F70);   // vmcnt(0)

    float hn = 0.f;
    float h0s=0.f, h1s=0.f, h2s=0.f;
    for (int chunk = 0; chunk < 32; ++chunk){
        if (chunk < 31){   // stage next chunk into the other buffer
            const float* nsrc = xdbl + (size_t)(b*SEQ + (chunk+1)*64)*32 + lane*4;
            float* nb = &bc[wv][(chunk+1)&1][0];
            #pragma unroll
            for (int k=0;k<8;++k)
                gload16f(nsrc + k*256, nb + k*256);
        }
        const float* cur = &bc[wv][chunk&1][0];
        float* hp = hsT + (size_t)(b*16 + i)*SEQ + chunk*64;
        float2 bc0 = *(const float2*)(cur + 2*i);          // step 0
        float2 bc1 = *(const float2*)(cur + 32 + 2*i);     // step 1
        #pragma unroll
        for (int st=0; st<64; ++st){
            float bv = bc0.x, cv = bc0.y;
            bc0 = bc1;
            if (st < 62)
                bc1 = *(const float2*)(cur + (st+2)*32 + 2*i);  // imm offset
            hn = scan_step_pk(hn, Wpk[st & 15], bv, cv);
            if ((st&3)==0)      h0s = hn;
            else if ((st&3)==1) h1s = hn;
            else if ((st&3)==2) h2s = hn;
            else if (lane < 16){
                float4 o4 = {h0s, h1s, h2s, hn};
                *(float4*)(hp + (st-3)) = o4;               // 1 store / 4 steps
            }
        }
        __builtin_amdgcn_s_waitcnt(0x0F70);   // vmcnt(0): next buffer staged
    }
}

// ---------------- y = repeat(hsT,128) + res (bf16) -------------------------
__global__ __launch_bounds__(256) void y_assemble(
    const float* __restrict__ hsT, const unsigned short* __restrict__ xr,
    unsigned short* __restrict__ y)
{
    int idx = blockIdx.x*256 + threadIdx.x;
    int r = idx >> 10;
    int c2 = (idx & 1023)*2;
    int bb = r >> 11, s = r & (SEQ-1);
    unsigned int u = *(const unsigned int*)(xr + (size_t)r*DFF + DINNER + c2);
    float h0 = hsT[(size_t)(bb*16 + (c2 >> 7))*SEQ + s];
    float y0 = h0 + b2f(u & 0xffff);
    float y1 = h0 + b2f(u >> 16);
    *(unsigned int*)(y + (size_t)r*DINNER + c2) =
        (unsigned int)f2b(y0) | ((unsigned int)f2b(y1) << 16);
}

// ---------------------------------------------------------------------------
extern "C" void kernel_launch(void* const* d_in, const int* in_sizes, int n_in,
                              void* d_out, int out_size, void* d_ws, size_t ws_size,
                              hipStream_t stream)
{
    (void)in_sizes; (void)n_in; (void)out_size; (void)ws_size;
    const float* x     = (const float*)d_in[0];
    const float* ln1_g = (const float*)d_in[1];
    const float* ln1_b = (const float*)d_in[2];
    const float* Wq    = (const float*)d_in[3];
    const float* bq    = (const float*)d_in[4];
    const float* Wk    = (const float*)d_in[5];
    const float* bk    = (const float*)d_in[6];
    const float* Wv    = (const float*)d_in[7];
    const float* bv    = (const float*)d_in[8];
    const float* Wo    = (const float*)d_in[9];
    const float* bo    = (const float*)d_in[10];
    const float* ln2_g = (const float*)d_in[11];
    const float* ln2_b = (const float*)d_in[12];
    const float* in_w  = (const float*)d_in[13];
    const float* in_b  = (const float*)d_in[14];
    const float* conv_w= (const float*)d_in[15];
    const float* conv_b= (const float*)d_in[16];
    const float* xp_w  = (const float*)d_in[17];
    const float* xp_b  = (const float*)d_in[18];
    const float* dt    = (const float*)d_in[19];
    const float* A     = (const float*)d_in[20];
    const float* out_w = (const float*)d_in[22];
    const float* out_b = (const float*)d_in[23];
    const float* ln3_g = (const float*)d_in[24];
    const float* ln3_b = (const float*)d_in[25];
    const float* fc1_w = (const float*)d_in[26];
    const float* fc1_b = (const float*)d_in[27];
    const float* fc2_w = (const float*)d_in[28];
    const float* fc2_b = (const float*)d_in[29];

    char* ws = (char*)d_ws;
    const size_t MB = 1ull << 20;
    unsigned short* qkvT = (unsigned short*)(ws + 0*MB);   // WqT|WkT|WvT, 6MB
    unsigned short* WoT  = (unsigned short*)(ws + 6*MB);
    unsigned short* inT  = (unsigned short*)(ws + 8*MB);
    unsigned short* outT = (unsigned short*)(ws + 16*MB);
    unsigned short* f1T  = (unsigned short*)(ws + 20*MB);
    unsigned short* f2T  = (unsigned short*)(ws + 28*MB);
    unsigned short* hbf  = (unsigned short*)(ws + 36*MB);
    float*          x2   = (float*)(ws + 44*MB);
    float*          x3   = (float*)(ws + 60*MB);
    unsigned short* qkv  = (unsigned short*)(ws + 76*MB);  // 24MB fused QKV
    unsigned short* attnb= (unsigned short*)(ws + 100*MB);
    unsigned short* xr   = (unsigned short*)(ws + 76*MB);  // reuse after attn
    unsigned short* ffn  = (unsigned short*)(ws + 76*MB);  // reuse after y
    unsigned short* xm2  = (unsigned short*)(ws + 108*MB);
    unsigned short* yb   = (unsigned short*)(ws + 108*MB); // reuse after xp
    float*          xdbl = (float*)(ws + 124*MB);
    float*          hsb  = (float*)(ws + 124*MB + 512*1024);
    float*          bqkv = (float*)(ws + 125*MB);

    dim3 blk(256);
    transpose_cast<<<dim3(16,16), blk, 0, stream>>>(Wq, qkvT,              1024, 1024);
    transpose_cast<<<dim3(16,16), blk, 0, stream>>>(Wk, qkvT + 1024*1024,  1024, 1024);
    transpose_cast<<<dim3(16,16), blk, 0, stream>>>(Wv, qkvT + 2*1024*1024,1024, 1024);
    transpose_cast<<<dim3(16,16), blk, 0, stream>>>(Wo, WoT, 1024, 1024);
    transpose_cast<<<dim3(64,16), blk, 0, stream>>>(in_w, inT, 1024, 4096);
    transpose_cast<<<dim3(16,32), blk, 0, stream>>>(out_w, outT, 2048, 1024);
    transpose_cast<<<dim3(64,16), blk, 0, stream>>>(fc1_w, f1T, 1024, 4096);
    transpose_cast<<<dim3(16,64), blk, 0, stream>>>(fc2_w, f2T, 4096, 1024);
    concat_bias<<<12, blk, 0, stream>>>(bq, bk, bv, bqkv);

    layernorm_bf16<<<MROWS, blk, 0, stream>>>(x, ln1_g, ln1_b, hbf);
    gemm_bt<128,1,0,0><<<dim3(24,32), blk, 0, stream>>>(hbf, qkvT, bqkv, nullptr, qkv, QKVLD, 1024);
    attn_flash<<<dim3(32,32), blk, 0, stream>>>(qkv, attnb);
    gemm_bt<64,0,1,0><<<dim3(16,32), blk, 0, stream>>>(attnb, WoT, bo, x, x2, 1024, 1024);
    layernorm_bf16<<<MROWS, blk, 0, stream>>>(x2, ln2_g, ln2_b, hbf);
    gemm_bt<128,1,0,0><<<dim3(32,32), blk, 0, stream>>>(hbf, inT, in_b, nullptr, xr, 4096, 1024);
    conv_silu<<<16384, blk, 0, stream>>>(xr, conv_w, conv_b, xm2);
    xp_gemm<<<512, blk, 0, stream>>>(xm2, xp_w, xp_b, xdbl);
    scan_k<<<1, dim3(128), 0, stream>>>(xdbl, dt, A, hsb);
    y_assemble<<<16384, blk, 0, stream>>>(hsb, xr, yb);
    gemm_bt<64,0,1,0><<<dim3(16,32), blk, 0, stream>>>(yb, outT, out_b, x2, x3, 1024, 2048);
    layernorm_bf16<<<MROWS, blk, 0, stream>>>(x3, ln3_g, ln3_b, hbf);
    gemm_bt<128,1,0,1><<<dim3(32,32), blk, 0, stream>>>(hbf, f1T, fc1_b, nullptr, ffn, 4096, 1024);
    gemm_bt<64,0,1,0><<<dim3(16,32), blk, 0, stream>>>(ffn, f2T, fc2_b, x3, (float*)d_out, 1024, 4096);
}